// Round 1
// baseline (605.558 us; speedup 1.0000x reference)
//
#include <hip/hip_runtime.h>

#define BB 256
#define LL 2048
#define HH 64
#define TT 64            // chunk length along L
#define SS 68            // padded LDS row stride (floats) for [TT][HH] tiles
#define NCH (LL / TT)    // 32 chunks
#define NTOT (BB * LL * 2)

__device__ __forceinline__ float sigmoidf_(float v) {
    return 1.0f / (1.0f + __expf(-v));
}

__global__ __launch_bounds__(256, 2)
void gru_fused(const float* __restrict__ x, const int* __restrict__ p,
               const float* __restrict__ w1z0, const float* __restrict__ b1z0,
               const float* __restrict__ w1h0, const float* __restrict__ b1h0,
               const float* __restrict__ w1z1, const float* __restrict__ b1z1,
               const float* __restrict__ w1h1, const float* __restrict__ b1h1,
               const float* __restrict__ w1o,  const float* __restrict__ b1o,
               const float* __restrict__ w2z0, const float* __restrict__ b2z0,
               const float* __restrict__ w2h0, const float* __restrict__ b2h0,
               const float* __restrict__ w2z1, const float* __restrict__ b2z1,
               const float* __restrict__ w2h1, const float* __restrict__ b2h1,
               const float* __restrict__ w2o,  const float* __restrict__ b2o,
               float* __restrict__ out)
{
    const int  b  = blockIdx.x;
    const bool pm = (blockIdx.y != 0);   // branch 1 = permuted input, weight set 2

    const float* wz0 = pm ? w2z0 : w1z0;
    const float* bz0 = pm ? b2z0 : b1z0;
    const float* wh0 = pm ? w2h0 : w1h0;
    const float* bh0 = pm ? b2h0 : b1h0;
    const float* wz1 = pm ? w2z1 : w1z1;
    const float* bz1 = pm ? b2z1 : b1z1;
    const float* wh1 = pm ? w2h1 : w1h1;
    const float* bh1 = pm ? b2h1 : b1h1;
    const float* wo  = pm ? w2o  : w1o;
    const float* bov = pm ? b2o  : b1o;

    const int tid = threadIdx.x;
    const int h   = tid & 63;    // hidden index (uniform within... varies per lane)
    const int tg  = tid >> 6;    // wave id 0..3 (uniform within a wave)

    __shared__ __align__(16) float s_a[TT * SS];
    __shared__ __align__(16) float s_b[TT * SS];
    __shared__ __align__(16) float s_h[TT * SS];
    __shared__ float s_x[TT];

    // per-thread layer-0 / bias params
    const float wz0h = wz0[h], bz0h = bz0[h];
    const float wh0h = wh0[h], bh0h = bh0[h];
    const float bz1h = bz1[h], bh1h = bh1[h];
    const float bo   = bov[0];

    // layer-1 weight columns in registers: rwz[k] = Wz1[k][h]
    float rwz[HH], rwh[HH];
    #pragma unroll
    for (int k = 0; k < HH; ++k) {
        rwz[k] = wz1[k * HH + h];
        rwh[k] = wh1[k * HH + h];
    }

    // phase-5 mapping: thread -> (t5, j5); j5 covers 16 k's of the output dot
    const int t5 = tid >> 2, j5 = tid & 3;
    float rwo[16];
    #pragma unroll
    for (int i = 0; i < 16; ++i) rwo[i] = wo[j5 * 16 + i];

    float carry0 = 0.0f, carry1 = 0.0f;   // scan state (valid in wave 0, tid<64)
    float* outp = out + (pm ? 1 : 0);

    for (int c = 0; c < NCH; ++c) {
        const int l0 = c * TT;

        // load x chunk (gathered for permuted branch)
        if (tid < TT) {
            const int l   = l0 + tid;
            const int src = pm ? p[l] : l;
            s_x[tid] = x[(size_t)b * LL + src];
        }
        __syncthreads();

        // phase 1: layer-0 gates (parallel, all 256 threads)
        #pragma unroll
        for (int j = 0; j < 16; ++j) {
            const int t = tg + 4 * j;
            const float xv  = s_x[t];                       // wave-uniform broadcast
            const float z   = sigmoidf_(fmaf(xv, wz0h, bz0h));
            const float htl = fmaf(xv, wh0h, bh0h);
            s_a[t * SS + h] = 1.0f - z;
            s_b[t * SS + h] = z * htl;
        }
        __syncthreads();

        // phase 2: layer-0 scan (wave 0, one lane per h)
        if (tid < HH) {
            float cc = carry0;
            #pragma unroll
            for (int t = 0; t < TT; ++t) {
                cc = fmaf(s_a[t * SS + h], cc, s_b[t * SS + h]);
                s_h[t * SS + h] = cc;
            }
            carry0 = cc;
        }
        __syncthreads();

        // phase 3: layer-1 matmuls + gates. Each thread: fixed h column (reg
        // weights), 16 t's; s_h reads are wave-uniform -> LDS broadcast (free).
        for (int ttn = 0; ttn < 16; ++ttn) {
            const int t = tg * 16 + ttn;
            float zacc = 0.0f, hacc = 0.0f;
            #pragma unroll
            for (int k4 = 0; k4 < 16; ++k4) {
                const float4 hv = *(const float4*)&s_h[t * SS + 4 * k4];
                zacc = fmaf(hv.x, rwz[4 * k4 + 0], zacc);
                hacc = fmaf(hv.x, rwh[4 * k4 + 0], hacc);
                zacc = fmaf(hv.y, rwz[4 * k4 + 1], zacc);
                hacc = fmaf(hv.y, rwh[4 * k4 + 1], hacc);
                zacc = fmaf(hv.z, rwz[4 * k4 + 2], zacc);
                hacc = fmaf(hv.z, rwh[4 * k4 + 2], hacc);
                zacc = fmaf(hv.w, rwz[4 * k4 + 3], zacc);
                hacc = fmaf(hv.w, rwh[4 * k4 + 3], hacc);
            }
            const float z   = sigmoidf_(zacc + bz1h);
            const float htl = hacc + bh1h;
            s_a[t * SS + h] = 1.0f - z;
            s_b[t * SS + h] = z * htl;
        }
        __syncthreads();

        // phase 4: layer-1 scan (wave 0)
        if (tid < HH) {
            float cc = carry1;
            #pragma unroll
            for (int t = 0; t < TT; ++t) {
                cc = fmaf(s_a[t * SS + h], cc, s_b[t * SS + h]);
                s_h[t * SS + h] = cc;   // h1 overwrites h0
            }
            carry1 = cc;
        }
        __syncthreads();

        // phase 5: output projection, 4 threads per t + shfl reduce
        {
            float acc = 0.0f;
            #pragma unroll
            for (int k4 = 0; k4 < 4; ++k4) {
                const float4 hv = *(const float4*)&s_h[t5 * SS + j5 * 16 + 4 * k4];
                acc = fmaf(hv.x, rwo[4 * k4 + 0], acc);
                acc = fmaf(hv.y, rwo[4 * k4 + 1], acc);
                acc = fmaf(hv.z, rwo[4 * k4 + 2], acc);
                acc = fmaf(hv.w, rwo[4 * k4 + 3], acc);
            }
            acc += __shfl_xor(acc, 1);
            acc += __shfl_xor(acc, 2);
            if (j5 == 0)
                outp[((size_t)b * LL + l0 + t5) * 2] = acc + bo;
        }
        __syncthreads();
    }
}

// per-block partial sums (sum, sumsq) over the raw outputs
__global__ void reduce_partial(const float* __restrict__ out, float* __restrict__ ws)
{
    const int per_block = NTOT / 256;           // 4096
    const int base = blockIdx.x * per_block;
    float s = 0.0f, s2 = 0.0f;
    for (int i = threadIdx.x; i < per_block; i += 256) {
        const float v = out[base + i];
        s += v;
        s2 = fmaf(v, v, s2);
    }
    #pragma unroll
    for (int o = 32; o; o >>= 1) {
        s  += __shfl_down(s, o);
        s2 += __shfl_down(s2, o);
    }
    __shared__ float ls[4], ls2[4];
    const int wid = threadIdx.x >> 6;
    if ((threadIdx.x & 63) == 0) { ls[wid] = s; ls2[wid] = s2; }
    __syncthreads();
    if (threadIdx.x == 0) {
        ws[blockIdx.x]       = ls[0] + ls[1] + ls[2] + ls[3];
        ws[256 + blockIdx.x] = ls2[0] + ls2[1] + ls2[2] + ls2[3];
    }
}

// every block redundantly folds the 256 partials, then normalizes its slice
__global__ void normalize_k(float* __restrict__ out, const float* __restrict__ ws)
{
    __shared__ float red[8];
    float s  = ws[threadIdx.x];
    float s2 = ws[256 + threadIdx.x];
    #pragma unroll
    for (int o = 32; o; o >>= 1) {
        s  += __shfl_down(s, o);
        s2 += __shfl_down(s2, o);
    }
    const int wid = threadIdx.x >> 6;
    if ((threadIdx.x & 63) == 0) { red[wid] = s; red[4 + wid] = s2; }
    __syncthreads();
    const float tot  = red[0] + red[1] + red[2] + red[3];
    const float tot2 = red[4] + red[5] + red[6] + red[7];
    const float N    = (float)NTOT;
    const float mean = tot / N;
    const float var  = (tot2 - N * mean * mean) / (N - 1.0f);
    const float inv  = rsqrtf(var);

    const int n4  = NTOT / 4;
    float4* o4 = (float4*)out;
    for (int i = blockIdx.x * blockDim.x + threadIdx.x; i < n4;
         i += gridDim.x * blockDim.x) {
        float4 v = o4[i];
        v.x = (v.x - mean) * inv;
        v.y = (v.y - mean) * inv;
        v.z = (v.z - mean) * inv;
        v.w = (v.w - mean) * inv;
        o4[i] = v;
    }
}

extern "C" void kernel_launch(void* const* d_in, const int* in_sizes, int n_in,
                              void* d_out, int out_size, void* d_ws, size_t ws_size,
                              hipStream_t stream)
{
    (void)in_sizes; (void)n_in; (void)out_size; (void)ws_size;
    const float* x = (const float*)d_in[0];
    const int*   p = (const int*)d_in[1];
    float* out = (float*)d_out;
    float* ws  = (float*)d_ws;

    dim3 grid(BB, 2);
    gru_fused<<<grid, 256, 0, stream>>>(
        x, p,
        (const float*)d_in[2],  (const float*)d_in[3],
        (const float*)d_in[4],  (const float*)d_in[5],
        (const float*)d_in[6],  (const float*)d_in[7],
        (const float*)d_in[8],  (const float*)d_in[9],
        (const float*)d_in[10], (const float*)d_in[11],
        (const float*)d_in[12], (const float*)d_in[13],
        (const float*)d_in[14], (const float*)d_in[15],
        (const float*)d_in[16], (const float*)d_in[17],
        (const float*)d_in[18], (const float*)d_in[19],
        (const float*)d_in[20], (const float*)d_in[21],
        out);

    reduce_partial<<<256, 256, 0, stream>>>(out, ws);
    normalize_k<<<1024, 256, 0, stream>>>(out, ws);
}

// Round 2
// 418.981 us; speedup vs baseline: 1.4453x; 1.4453x over previous
//
#include <hip/hip_runtime.h>

#define BB 256
#define LL 2048
#define HH 64
#define TT 64            // chunk length along L
#define SS 68            // padded LDS row stride (floats) for [TT][HH] tiles
#define NCH (LL / TT)    // 32 chunks
#define NTOT (BB * LL * 2)

typedef __attribute__((ext_vector_type(8))) short bf16x8;
typedef __attribute__((ext_vector_type(4))) float f32x4;

__device__ __forceinline__ float sigmoidf_(float v) {
    return 1.0f / (1.0f + __expf(-v));
}

// fp32 -> bf16 bits, round-to-nearest-even (finite inputs)
__device__ __forceinline__ short f2bf(float f) {
    union { float f; unsigned u; } v; v.f = f;
    unsigned r = v.u + 0x7fff + ((v.u >> 16) & 1);
    return (short)(r >> 16);
}
__device__ __forceinline__ float bf2f(short s) {
    union { unsigned u; float f; } v;
    v.u = ((unsigned)(unsigned short)s) << 16;
    return v.f;
}

__global__ __launch_bounds__(256, 2)
void gru_fused(const float* __restrict__ x, const int* __restrict__ p,
               const float* __restrict__ w1z0, const float* __restrict__ b1z0,
               const float* __restrict__ w1h0, const float* __restrict__ b1h0,
               const float* __restrict__ w1z1, const float* __restrict__ b1z1,
               const float* __restrict__ w1h1, const float* __restrict__ b1h1,
               const float* __restrict__ w1o,  const float* __restrict__ b1o,
               const float* __restrict__ w2z0, const float* __restrict__ b2z0,
               const float* __restrict__ w2h0, const float* __restrict__ b2h0,
               const float* __restrict__ w2z1, const float* __restrict__ b2z1,
               const float* __restrict__ w2h1, const float* __restrict__ b2h1,
               const float* __restrict__ w2o,  const float* __restrict__ b2o,
               float* __restrict__ out, float* __restrict__ ws)
{
    const int  b  = blockIdx.x;
    const bool pm = (blockIdx.y != 0);   // branch 1 = permuted input, weight set 2

    const float* wz0 = pm ? w2z0 : w1z0;
    const float* bz0 = pm ? b2z0 : b1z0;
    const float* wh0 = pm ? w2h0 : w1h0;
    const float* bh0 = pm ? b2h0 : b1h0;
    const float* wz1 = pm ? w2z1 : w1z1;
    const float* bz1 = pm ? b2z1 : b1z1;
    const float* wh1 = pm ? w2h1 : w1h1;
    const float* bh1 = pm ? b2h1 : b1h1;
    const float* wo  = pm ? w2o  : w1o;
    const float* bov = pm ? b2o  : b1o;

    const int tid  = threadIdx.x;
    const int lane = tid & 63;
    const int tg   = tid >> 6;          // wave id 0..3 -> owns t rows [16*tg, 16*tg+16)
    const int q    = lane >> 4;         // MFMA quad
    const int n    = lane & 15;         // MFMA col-in-tile

    __shared__ __align__(16) float s_a[TT * SS];
    __shared__ __align__(16) float s_b[TT * SS];
    __shared__ __align__(16) float s_h[TT * SS];
    __shared__ float s_red[8];

    // ---- layer-0 LUT (x is bernoulli {0,1}): per lane h = lane ----
    const float z0v = sigmoidf_(bz0[lane]);
    const float z1v = sigmoidf_(wz0[lane] + bz0[lane]);
    const float a0v = 1.0f - z0v, b0v = z0v * bh0[lane];
    const float a1v = 1.0f - z1v, b1v = z1v * (wh0[lane] + bh0[lane]);

    // ---- layer-1 bias per lane (per h-tile) ----
    float rbz1[4], rbh1[4];
    #pragma unroll
    for (int ht = 0; ht < 4; ++ht) {
        rbz1[ht] = bz1[ht * 16 + n];
        rbh1[ht] = bh1[ht * 16 + n];
    }
    const float bo = bov[0];

    // ---- layer-1 weight B-fragments in registers (hi/lo bf16 split) ----
    // B[k][h]: lane holds W[k0 + q*8 + j][h0 + n], j = 0..7
    bf16x8 wfz_hi[2][4], wfz_lo[2][4], wfh_hi[2][4], wfh_lo[2][4];
    for (int ks = 0; ks < 2; ++ks) {
        for (int ht = 0; ht < 4; ++ht) {
            #pragma unroll
            for (int j = 0; j < 8; ++j) {
                const int kk = ks * 32 + q * 8 + j;
                const int hh = ht * 16 + n;
                const float wz = wz1[kk * HH + hh];
                const short zh = f2bf(wz);
                wfz_hi[ks][ht][j] = zh;
                wfz_lo[ks][ht][j] = f2bf(wz - bf2f(zh));
                const float wh = wh1[kk * HH + hh];
                const short hh2 = f2bf(wh);
                wfh_hi[ks][ht][j] = hh2;
                wfh_lo[ks][ht][j] = f2bf(wh - bf2f(hh2));
            }
        }
    }

    // ---- phase-5 mapping and output weights ----
    const int t5 = tid >> 2, j5 = tid & 3;
    float rwo[16];
    #pragma unroll
    for (int i = 0; i < 16; ++i) rwo[i] = wo[j5 * 16 + i];

    float carry0 = 0.0f, carry1 = 0.0f;   // scan state (valid in wave 0)
    float lsum = 0.0f, lsum2 = 0.0f;      // local partial sums of raw outputs
    float* outp = out + (pm ? 1 : 0);
    const int t0 = tg * 16;

    for (int c = 0; c < NCH; ++c) {
        const int l0 = c * TT;

        // phase 1: layer-0 gates via bit-select; wave tg covers t rows t0..t0+15
        {
            const int tl  = l0 + t0 + n;     // lanes 0-15 carry the 16 x values
            const int src = pm ? p[tl] : tl;
            const float xv16 = x[(size_t)b * LL + src];
            #pragma unroll
            for (int j = 0; j < 16; ++j) {
                const float xv = __shfl(xv16, j);
                const bool  on = (xv != 0.0f);
                const int   t  = t0 + j;
                s_a[t * SS + lane] = on ? a1v : a0v;
                s_b[t * SS + lane] = on ? b1v : b0v;
            }
        }
        __syncthreads();

        // phase 2: layer-0 scan (wave 0, one lane per h)
        if (tid < HH) {
            float cc = carry0;
            #pragma unroll
            for (int t = 0; t < TT; ++t) {
                cc = fmaf(s_a[t * SS + lane], cc, s_b[t * SS + lane]);
                s_h[t * SS + lane] = cc;
            }
            carry0 = cc;
        }
        __syncthreads();

        // phase 3: layer-1 matmuls on MFMA (3-term hi/lo split), wave tg does
        // t rows [t0, t0+16) x all 64 h
        {
            f32x4 accz[4], acch[4];
            #pragma unroll
            for (int ht = 0; ht < 4; ++ht) {
                accz[ht] = (f32x4){rbz1[ht], rbz1[ht], rbz1[ht], rbz1[ht]};
                acch[ht] = (f32x4){rbh1[ht], rbh1[ht], rbh1[ht], rbh1[ht]};
            }
            #pragma unroll
            for (int ks = 0; ks < 2; ++ks) {
                // A[m][k]: lane holds Hs[t0+n][ks*32 + q*8 + j]
                const float* ap = &s_h[(t0 + n) * SS + ks * 32 + q * 8];
                const float4 av0 = *(const float4*)ap;
                const float4 av1 = *(const float4*)(ap + 4);
                float af[8] = {av0.x, av0.y, av0.z, av0.w, av1.x, av1.y, av1.z, av1.w};
                bf16x8 ahi, alo;
                #pragma unroll
                for (int j = 0; j < 8; ++j) {
                    const short h16 = f2bf(af[j]);
                    ahi[j] = h16;
                    alo[j] = f2bf(af[j] - bf2f(h16));
                }
                #pragma unroll
                for (int ht = 0; ht < 4; ++ht) {
                    accz[ht] = __builtin_amdgcn_mfma_f32_16x16x32_bf16(ahi, wfz_hi[ks][ht], accz[ht], 0, 0, 0);
                    accz[ht] = __builtin_amdgcn_mfma_f32_16x16x32_bf16(alo, wfz_hi[ks][ht], accz[ht], 0, 0, 0);
                    accz[ht] = __builtin_amdgcn_mfma_f32_16x16x32_bf16(ahi, wfz_lo[ks][ht], accz[ht], 0, 0, 0);
                    acch[ht] = __builtin_amdgcn_mfma_f32_16x16x32_bf16(ahi, wfh_hi[ks][ht], acch[ht], 0, 0, 0);
                    acch[ht] = __builtin_amdgcn_mfma_f32_16x16x32_bf16(alo, wfh_hi[ks][ht], acch[ht], 0, 0, 0);
                    acch[ht] = __builtin_amdgcn_mfma_f32_16x16x32_bf16(ahi, wfh_lo[ks][ht], acch[ht], 0, 0, 0);
                }
            }
            // epilogue: gates -> s_a/s_b.  C/D: row = q*4+reg, col = n
            #pragma unroll
            for (int ht = 0; ht < 4; ++ht) {
                #pragma unroll
                for (int r = 0; r < 4; ++r) {
                    const float z   = sigmoidf_(accz[ht][r]);
                    const float htl = acch[ht][r];
                    const int   t   = t0 + q * 4 + r;
                    s_a[t * SS + ht * 16 + n] = 1.0f - z;
                    s_b[t * SS + ht * 16 + n] = z * htl;
                }
            }
        }
        __syncthreads();

        // phase 4: layer-1 scan (wave 0)
        if (tid < HH) {
            float cc = carry1;
            #pragma unroll
            for (int t = 0; t < TT; ++t) {
                cc = fmaf(s_a[t * SS + lane], cc, s_b[t * SS + lane]);
                s_h[t * SS + lane] = cc;
            }
            carry1 = cc;
        }
        __syncthreads();

        // phase 5: output projection, 4 threads per t + shfl reduce
        {
            float acc = 0.0f;
            #pragma unroll
            for (int k4 = 0; k4 < 4; ++k4) {
                const float4 hv = *(const float4*)&s_h[t5 * SS + j5 * 16 + 4 * k4];
                acc = fmaf(hv.x, rwo[4 * k4 + 0], acc);
                acc = fmaf(hv.y, rwo[4 * k4 + 1], acc);
                acc = fmaf(hv.z, rwo[4 * k4 + 2], acc);
                acc = fmaf(hv.w, rwo[4 * k4 + 3], acc);
            }
            acc += __shfl_xor(acc, 1);
            acc += __shfl_xor(acc, 2);
            if (j5 == 0) {
                const float v = acc + bo;
                outp[((size_t)b * LL + l0 + t5) * 2] = v;
                lsum += v;
                lsum2 = fmaf(v, v, lsum2);
            }
        }
        // no barrier needed here: next phase-1 writes race with nothing live
    }

    // ---- block-level partial (sum, sumsq) -> global atomics ----
    #pragma unroll
    for (int o = 32; o; o >>= 1) {
        lsum  += __shfl_down(lsum, o);
        lsum2 += __shfl_down(lsum2, o);
    }
    if (lane == 0) { s_red[tg] = lsum; s_red[4 + tg] = lsum2; }
    __syncthreads();
    if (tid == 0) {
        atomicAdd(&ws[0], s_red[0] + s_red[1] + s_red[2] + s_red[3]);
        atomicAdd(&ws[1], s_red[4] + s_red[5] + s_red[6] + s_red[7]);
    }
}

// every block reads the two totals, then normalizes its slice in-place
__global__ void normalize_k(float* __restrict__ out, const float* __restrict__ ws)
{
    const float tot  = ws[0];
    const float tot2 = ws[1];
    const float N    = (float)NTOT;
    const float mean = tot / N;
    const float var  = (tot2 - N * mean * mean) / (N - 1.0f);
    const float inv  = rsqrtf(var);

    const int n4 = NTOT / 4;
    float4* o4 = (float4*)out;
    for (int i = blockIdx.x * blockDim.x + threadIdx.x; i < n4;
         i += gridDim.x * blockDim.x) {
        float4 v = o4[i];
        v.x = (v.x - mean) * inv;
        v.y = (v.y - mean) * inv;
        v.z = (v.z - mean) * inv;
        v.w = (v.w - mean) * inv;
        o4[i] = v;
    }
}

extern "C" void kernel_launch(void* const* d_in, const int* in_sizes, int n_in,
                              void* d_out, int out_size, void* d_ws, size_t ws_size,
                              hipStream_t stream)
{
    (void)in_sizes; (void)n_in; (void)out_size; (void)ws_size;
    const float* x = (const float*)d_in[0];
    const int*   p = (const int*)d_in[1];
    float* out = (float*)d_out;
    float* ws  = (float*)d_ws;

    hipMemsetAsync(ws, 0, 2 * sizeof(float), stream);

    dim3 grid(BB, 2);
    gru_fused<<<grid, 256, 0, stream>>>(
        x, p,
        (const float*)d_in[2],  (const float*)d_in[3],
        (const float*)d_in[4],  (const float*)d_in[5],
        (const float*)d_in[6],  (const float*)d_in[7],
        (const float*)d_in[8],  (const float*)d_in[9],
        (const float*)d_in[10], (const float*)d_in[11],
        (const float*)d_in[12], (const float*)d_in[13],
        (const float*)d_in[14], (const float*)d_in[15],
        (const float*)d_in[16], (const float*)d_in[17],
        (const float*)d_in[18], (const float*)d_in[19],
        (const float*)d_in[20], (const float*)d_in[21],
        out, ws);

    normalize_k<<<1024, 256, 0, stream>>>(out, ws);
}

// Round 3
// 280.381 us; speedup vs baseline: 2.1598x; 1.4943x over previous
//
#include <hip/hip_runtime.h>

#define BB 256
#define LL 2048
#define HH 64
#define TT 64            // chunk length along L
#define SS 68            // padded LDS row stride (floats)
#define NCH (LL / TT)    // 32 chunks
#define NTOT (BB * LL * 2)

typedef __attribute__((ext_vector_type(8))) short bf16x8;
typedef __attribute__((ext_vector_type(4))) float f32x4;

__device__ __forceinline__ float sigmoidf_(float v) {
    return 1.0f / (1.0f + __expf(-v));
}
__device__ __forceinline__ short f2bf(float f) {
    union { float f; unsigned u; } v; v.f = f;
    unsigned r = v.u + 0x7fff + ((v.u >> 16) & 1);
    return (short)(r >> 16);
}
__device__ __forceinline__ float bf2f(short s) {
    union { unsigned u; float f; } v;
    v.u = ((unsigned)(unsigned short)s) << 16;
    return v.f;
}

__global__ __launch_bounds__(256, 2)
void gru_fused(const float* __restrict__ x, const int* __restrict__ p,
               const float* __restrict__ w1z0, const float* __restrict__ b1z0,
               const float* __restrict__ w1h0, const float* __restrict__ b1h0,
               const float* __restrict__ w1z1, const float* __restrict__ b1z1,
               const float* __restrict__ w1h1, const float* __restrict__ b1h1,
               const float* __restrict__ w1o,  const float* __restrict__ b1o,
               const float* __restrict__ w2z0, const float* __restrict__ b2z0,
               const float* __restrict__ w2h0, const float* __restrict__ b2h0,
               const float* __restrict__ w2z1, const float* __restrict__ b2z1,
               const float* __restrict__ w2h1, const float* __restrict__ b2h1,
               const float* __restrict__ w2o,  const float* __restrict__ b2o,
               float* __restrict__ out, float* __restrict__ ws)
{
    const int  b  = blockIdx.x;
    const bool pm = (blockIdx.y != 0);

    const float* wz0 = pm ? w2z0 : w1z0;
    const float* bz0 = pm ? b2z0 : b1z0;
    const float* wh0 = pm ? w2h0 : w1h0;
    const float* bh0 = pm ? b2h0 : b1h0;
    const float* wz1 = pm ? w2z1 : w1z1;
    const float* bz1 = pm ? b2z1 : b1z1;
    const float* wh1 = pm ? w2h1 : w1h1;
    const float* bh1 = pm ? b2h1 : b1h1;
    const float* wo  = pm ? w2o  : w1o;
    const float* bov = pm ? b2o  : b1o;

    const int tid  = threadIdx.x;
    const int lane = tid & 63;
    const int tg   = tid >> 6;
    const int q    = lane >> 4;
    const int n    = lane & 15;
    const int seg  = lane & 3;
    const int hidx = (tg << 4) | (lane >> 2);

    __shared__ __align__(16) float s_h[TT * SS];
    __shared__ __align__(16) float s_at[HH * SS];
    __shared__ __align__(16) float s_bt[HH * SS];
    __shared__ float s_red[8];

    const float z0v = sigmoidf_(bz0[hidx]);
    const float z1v = sigmoidf_(wz0[hidx] + bz0[hidx]);
    const float a0v = 1.0f - z0v, b0v = z0v * bh0[hidx];
    const float a1v = 1.0f - z1v, b1v = z1v * (wh0[hidx] + bh0[hidx]);

    float rbz1[4], rbh1[4];
    #pragma unroll
    for (int ht = 0; ht < 4; ++ht) {
        rbz1[ht] = bz1[ht * 16 + n];
        rbh1[ht] = bh1[ht * 16 + n];
    }
    const float bo = bov[0];

    bf16x8 wfz_hi[2][4], wfz_lo[2][4], wfh_hi[2][4], wfh_lo[2][4];
    for (int ks = 0; ks < 2; ++ks) {
        for (int ht = 0; ht < 4; ++ht) {
            #pragma unroll
            for (int j = 0; j < 8; ++j) {
                const int kk = ks * 32 + q * 8 + j;
                const int hh = ht * 16 + n;
                const float wz = wz1[kk * HH + hh];
                const short zh = f2bf(wz);
                wfz_hi[ks][ht][j] = zh;
                wfz_lo[ks][ht][j] = f2bf(wz - bf2f(zh));
                const float wh = wh1[kk * HH + hh];
                const short hh2 = f2bf(wh);
                wfh_hi[ks][ht][j] = hh2;
                wfh_lo[ks][ht][j] = f2bf(wh - bf2f(hh2));
            }
        }
    }

    const int t5 = tid >> 2, j5 = tid & 3;
    float rwo[16];
    #pragma unroll
    for (int i = 0; i < 16; ++i) rwo[i] = wo[j5 * 16 + i];

    float carry0 = 0.0f, carry1 = 0.0f;
    float lsum = 0.0f, lsum2 = 0.0f;
    float* outp = out + (pm ? 1 : 0);
    const int t0 = tg * 16;

    for (int c = 0; c < NCH; ++c) {
        const int l0 = c * TT;

        // ---- P1: layer-0 gates + parallel scan (registers + quad shfl) ----
        {
            float ai[16], bi[16];
            float A = 1.0f, Bv = 0.0f;
            const int tbase = l0 + seg * 16;
            #pragma unroll
            for (int i = 0; i < 16; ++i) {
                const int t  = tbase + i;
                const int sr = pm ? p[t] : t;
                const float xv = x[(size_t)b * LL + sr];
                const bool on  = (xv != 0.0f);
                ai[i] = on ? a1v : a0v;
                bi[i] = on ? b1v : b0v;
                A  = A * ai[i];
                Bv = fmaf(Bv, ai[i], bi[i]);
            }
            {
                const float Au = __shfl_up(A, 1, 4), Bu = __shfl_up(Bv, 1, 4);
                if (seg >= 1) { const float Ac = A; A = Au * Ac; Bv = fmaf(Bu, Ac, Bv); }
                const float Au2 = __shfl_up(A, 2, 4), Bu2 = __shfl_up(Bv, 2, 4);
                if (seg >= 2) { const float Ac = A; A = Au2 * Ac; Bv = fmaf(Bu2, Ac, Bv); }
            }
            float Ae = __shfl_up(A, 1, 4), Be = __shfl_up(Bv, 1, 4);
            if (seg == 0) { Ae = 1.0f; Be = 0.0f; }
            float cc = fmaf(Ae, carry0, Be);
            #pragma unroll
            for (int i = 0; i < 16; ++i) {
                cc = fmaf(ai[i], cc, bi[i]);
                s_h[(seg * 16 + i) * SS + hidx] = cc;
            }
            carry0 = __shfl(cc, lane | 3);
        }
        __syncthreads();

        // ---- P3: layer-1 matmuls on MFMA ----
        {
            f32x4 accz[4], acch[4];
            #pragma unroll
            for (int ht = 0; ht < 4; ++ht) {
                accz[ht] = (f32x4){rbz1[ht], rbz1[ht], rbz1[ht], rbz1[ht]};
                acch[ht] = (f32x4){rbh1[ht], rbh1[ht], rbh1[ht], rbh1[ht]};
            }
            #pragma unroll
            for (int ks = 0; ks < 2; ++ks) {
                const float* ap = &s_h[(t0 + n) * SS + ks * 32 + q * 8];
                const float4 av0 = *(const float4*)ap;
                const float4 av1 = *(const float4*)(ap + 4);
                float af[8] = {av0.x, av0.y, av0.z, av0.w, av1.x, av1.y, av1.z, av1.w};
                bf16x8 ahi, alo;
                #pragma unroll
                for (int j = 0; j < 8; ++j) {
                    const short h16 = f2bf(af[j]);
                    ahi[j] = h16;
                    alo[j] = f2bf(af[j] - bf2f(h16));
                }
                #pragma unroll
                for (int ht = 0; ht < 4; ++ht) {
                    accz[ht] = __builtin_amdgcn_mfma_f32_16x16x32_bf16(ahi, wfz_hi[ks][ht], accz[ht], 0, 0, 0);
                    accz[ht] = __builtin_amdgcn_mfma_f32_16x16x32_bf16(alo, wfz_hi[ks][ht], accz[ht], 0, 0, 0);
                    accz[ht] = __builtin_amdgcn_mfma_f32_16x16x32_bf16(ahi, wfz_lo[ks][ht], accz[ht], 0, 0, 0);
                    acch[ht] = __builtin_amdgcn_mfma_f32_16x16x32_bf16(ahi, wfh_hi[ks][ht], acch[ht], 0, 0, 0);
                    acch[ht] = __builtin_amdgcn_mfma_f32_16x16x32_bf16(alo, wfh_hi[ks][ht], acch[ht], 0, 0, 0);
                    acch[ht] = __builtin_amdgcn_mfma_f32_16x16x32_bf16(ahi, wfh_lo[ks][ht], acch[ht], 0, 0, 0);
                }
            }
            #pragma unroll
            for (int ht = 0; ht < 4; ++ht) {
                float4 av, bv4;
                float* avp = (float*)&av; float* bvp = (float*)&bv4;
                #pragma unroll
                for (int r = 0; r < 4; ++r) {
                    const float z = sigmoidf_(accz[ht][r]);
                    avp[r] = 1.0f - z;
                    bvp[r] = z * acch[ht][r];
                }
                const int row = ht * 16 + n;
                *(float4*)&s_at[row * SS + t0 + q * 4] = av;
                *(float4*)&s_bt[row * SS + t0 + q * 4] = bv4;
            }
        }
        __syncthreads();

        // ---- P4: layer-1 parallel scan ----
        {
            float ai[16], bi[16];
            #pragma unroll
            for (int j4 = 0; j4 < 4; ++j4) {
                const float4 av = *(const float4*)&s_at[hidx * SS + seg * 16 + 4 * j4];
                const float4 bv = *(const float4*)&s_bt[hidx * SS + seg * 16 + 4 * j4];
                ai[4 * j4 + 0] = av.x; ai[4 * j4 + 1] = av.y;
                ai[4 * j4 + 2] = av.z; ai[4 * j4 + 3] = av.w;
                bi[4 * j4 + 0] = bv.x; bi[4 * j4 + 1] = bv.y;
                bi[4 * j4 + 2] = bv.z; bi[4 * j4 + 3] = bv.w;
            }
            float A = 1.0f, Bv = 0.0f;
            #pragma unroll
            for (int i = 0; i < 16; ++i) {
                A  = A * ai[i];
                Bv = fmaf(Bv, ai[i], bi[i]);
            }
            {
                const float Au = __shfl_up(A, 1, 4), Bu = __shfl_up(Bv, 1, 4);
                if (seg >= 1) { const float Ac = A; A = Au * Ac; Bv = fmaf(Bu, Ac, Bv); }
                const float Au2 = __shfl_up(A, 2, 4), Bu2 = __shfl_up(Bv, 2, 4);
                if (seg >= 2) { const float Ac = A; A = Au2 * Ac; Bv = fmaf(Bu2, Ac, Bv); }
            }
            float Ae = __shfl_up(A, 1, 4), Be = __shfl_up(Bv, 1, 4);
            if (seg == 0) { Ae = 1.0f; Be = 0.0f; }
            float cc = fmaf(Ae, carry1, Be);
            #pragma unroll
            for (int i = 0; i < 16; ++i) {
                cc = fmaf(ai[i], cc, bi[i]);
                s_h[(seg * 16 + i) * SS + hidx] = cc;
            }
            carry1 = __shfl(cc, lane | 3);
        }
        __syncthreads();

        // ---- P5: output projection ----
        {
            float acc = 0.0f;
            #pragma unroll
            for (int k4 = 0; k4 < 4; ++k4) {
                const float4 hv = *(const float4*)&s_h[t5 * SS + j5 * 16 + 4 * k4];
                acc = fmaf(hv.x, rwo[4 * k4 + 0], acc);
                acc = fmaf(hv.y, rwo[4 * k4 + 1], acc);
                acc = fmaf(hv.z, rwo[4 * k4 + 2], acc);
                acc = fmaf(hv.w, rwo[4 * k4 + 3], acc);
            }
            acc += __shfl_xor(acc, 1);
            acc += __shfl_xor(acc, 2);
            if (j5 == 0) {
                const float v = acc + bo;
                outp[((size_t)b * LL + l0 + t5) * 2] = v;
                lsum += v;
                lsum2 = fmaf(v, v, lsum2);
            }
        }
        __syncthreads();
    }

    #pragma unroll
    for (int o = 32; o; o >>= 1) {
        lsum  += __shfl_down(lsum, o);
        lsum2 += __shfl_down(lsum2, o);
    }
    if (lane == 0) { s_red[tg] = lsum; s_red[4 + tg] = lsum2; }
    __syncthreads();
    if (tid == 0) {
        atomicAdd(&ws[0], s_red[0] + s_red[1] + s_red[2] + s_red[3]);
        atomicAdd(&ws[1], s_red[4] + s_red[5] + s_red[6] + s_red[7]);
    }
}

__global__ void normalize_k(float* __restrict__ out, const float* __restrict__ ws)
{
    const float tot  = ws[0];
    const float tot2 = ws[1];
    const float N    = (float)NTOT;
    const float mean = tot / N;
    const float var  = (tot2 - N * mean * mean) / (N - 1.0f);
    const float inv  = rsqrtf(var);

    const int n4 = NTOT / 4;
    float4* o4 = (float4*)out;
    for (int i = blockIdx.x * blockDim.x + threadIdx.x; i < n4;
         i += gridDim.x * blockDim.x) {
        float4 v = o4[i];
        v.x = (v.x - mean) * inv;
        v.y = (v.y - mean) * inv;
        v.z = (v.z - mean) * inv;
        v.w = (v.w - mean) * inv;
        o4[i] = v;
    }
}

extern "C" void kernel_launch(void* const* d_in, const int* in_sizes, int n_in,
                              void* d_out, int out_size, void* d_ws, size_t ws_size,
                              hipStream_t stream)
{
    (void)in_sizes; (void)n_in; (void)out_size; (void)ws_size;
    const float* x = (const float*)d_in[0];
    const int*   p = (const int*)d_in[1];
    float* out = (float*)d_out;
    float* ws  = (float*)d_ws;

    hipMemsetAsync(ws, 0, 2 * sizeof(float), stream);

    dim3 grid(BB, 2);
    gru_fused<<<grid, 256, 0, stream>>>(
        x, p,
        (const float*)d_in[2],  (const float*)d_in[3],
        (const float*)d_in[4],  (const float*)d_in[5],
        (const float*)d_in[6],  (const float*)d_in[7],
        (const float*)d_in[8],  (const float*)d_in[9],
        (const float*)d_in[10], (const float*)d_in[11],
        (const float*)d_in[12], (const float*)d_in[13],
        (const float*)d_in[14], (const float*)d_in[15],
        (const float*)d_in[16], (const float*)d_in[17],
        (const float*)d_in[18], (const float*)d_in[19],
        (const float*)d_in[20], (const float*)d_in[21],
        out, ws);

    normalize_k<<<1024, 256, 0, stream>>>(out, ws);
}

// Round 5
// 277.630 us; speedup vs baseline: 2.1812x; 1.0099x over previous
//
#include <hip/hip_runtime.h>

#define BB 256
#define LL 2048
#define HH 64
#define TT 64            // chunk length along L
#define SS 68            // padded LDS row stride (floats)
#define NCH (LL / TT)    // 32 chunks
#define NTOT (BB * LL * 2)

typedef __attribute__((ext_vector_type(8))) short bf16x8;
typedef __attribute__((ext_vector_type(4))) float f32x4;

__device__ __forceinline__ float sigmoidf_(float v) {
    return 1.0f / (1.0f + __expf(-v));
}
__device__ __forceinline__ short f2bf(float f) {
    union { float f; unsigned u; } v; v.f = f;
    unsigned r = v.u + 0x7fff + ((v.u >> 16) & 1);
    return (short)(r >> 16);
}
__device__ __forceinline__ float bf2f(short s) {
    union { unsigned u; float f; } v;
    v.u = ((unsigned)(unsigned short)s) << 16;
    return v.f;
}

// Vectorized x-chunk load: 16 consecutive t starting at tb (tb % 16 == 0).
__device__ __forceinline__ void load_x(const float* __restrict__ xrow,
                                       const int* __restrict__ p,
                                       bool pm, int tb, float* xv)
{
    if (!pm) {
        const float4* x4 = (const float4*)(xrow + tb);
        #pragma unroll
        for (int k = 0; k < 4; ++k) {
            const float4 v = x4[k];
            xv[4*k+0] = v.x; xv[4*k+1] = v.y; xv[4*k+2] = v.z; xv[4*k+3] = v.w;
        }
    } else {
        const int4* p4 = (const int4*)(p + tb);
        int idx[16];
        #pragma unroll
        for (int k = 0; k < 4; ++k) {
            const int4 v = p4[k];
            idx[4*k+0] = v.x; idx[4*k+1] = v.y; idx[4*k+2] = v.z; idx[4*k+3] = v.w;
        }
        #pragma unroll
        for (int i = 0; i < 16; ++i) xv[i] = xrow[idx[i]];
    }
}

// Layer-0 gates from Bernoulli LUT + 64-step scan (16 local + quad Hillis-Steele),
// writes h0 to sh with the bit4 column swizzle.
__device__ __forceinline__ void p1_scan(const float* xv,
                                        float a0v, float b0v, float a1v, float b1v,
                                        int seg, int col0, float& carry, float* sh)
{
    float ai[16], bi[16];
    float A = 1.0f, Bv = 0.0f;
    #pragma unroll
    for (int i = 0; i < 16; ++i) {
        const bool on = (xv[i] != 0.0f);
        ai[i] = on ? a1v : a0v;
        bi[i] = on ? b1v : b0v;
        A  = A * ai[i];
        Bv = fmaf(Bv, ai[i], bi[i]);
    }
    {
        const float Au = __shfl_up(A, 1, 4), Bu = __shfl_up(Bv, 1, 4);
        if (seg >= 1) { const float Ac = A; A = Au * Ac; Bv = fmaf(Bu, Ac, Bv); }
        const float Au2 = __shfl_up(A, 2, 4), Bu2 = __shfl_up(Bv, 2, 4);
        if (seg >= 2) { const float Ac = A; A = Au2 * Ac; Bv = fmaf(Bu2, Ac, Bv); }
    }
    float Ae = __shfl_up(A, 1, 4), Be = __shfl_up(Bv, 1, 4);
    if (seg == 0) { Ae = 1.0f; Be = 0.0f; }
    float cc = fmaf(Ae, carry, Be);
    #pragma unroll
    for (int i = 0; i < 16; ++i) {
        cc = fmaf(ai[i], cc, bi[i]);
        sh[(seg * 16 + i) * SS + col0] = cc;
    }
    carry = __shfl(cc, (int)(threadIdx.x & 63) | 3);
}

// Distributed butterfly: v[16] per lane; sums index i across the 16 quad-groups
// (lane bits 2-5), preserving lane&3. Lane ends with the full sum for i == lane>>2.
__device__ __forceinline__ float reduce16_quadgroups(const float* v, int m) {
    float a[8];
    #pragma unroll
    for (int k = 0; k < 8; ++k) {
        const float keep = (m & 1) ? v[2*k+1] : v[2*k];
        const float send = (m & 1) ? v[2*k]   : v[2*k+1];
        a[k] = keep + __shfl_xor(send, 4);
    }
    float b2[4];
    #pragma unroll
    for (int k = 0; k < 4; ++k) {
        const float keep = (m & 2) ? a[2*k+1] : a[2*k];
        const float send = (m & 2) ? a[2*k]   : a[2*k+1];
        b2[k] = keep + __shfl_xor(send, 8);
    }
    float c2[2];
    #pragma unroll
    for (int k = 0; k < 2; ++k) {
        const float keep = (m & 4) ? b2[2*k+1] : b2[2*k];
        const float send = (m & 4) ? b2[2*k]   : b2[2*k+1];
        c2[k] = keep + __shfl_xor(send, 16);
    }
    const float keep = (m & 8) ? c2[1] : c2[0];
    const float send = (m & 8) ? c2[0] : c2[1];
    return keep + __shfl_xor(send, 32);
}

__global__ __launch_bounds__(256, 2)
void gru_fused(const float* __restrict__ x, const int* __restrict__ p,
               const float* __restrict__ w1z0, const float* __restrict__ b1z0,
               const float* __restrict__ w1h0, const float* __restrict__ b1h0,
               const float* __restrict__ w1z1, const float* __restrict__ b1z1,
               const float* __restrict__ w1h1, const float* __restrict__ b1h1,
               const float* __restrict__ w1o,  const float* __restrict__ b1o,
               const float* __restrict__ w2z0, const float* __restrict__ b2z0,
               const float* __restrict__ w2h0, const float* __restrict__ b2h0,
               const float* __restrict__ w2z1, const float* __restrict__ b2z1,
               const float* __restrict__ w2h1, const float* __restrict__ b2h1,
               const float* __restrict__ w2o,  const float* __restrict__ b2o,
               float* __restrict__ out, float* __restrict__ ws)
{
    const int  b  = blockIdx.x;
    const bool pm = (blockIdx.y != 0);

    const float* wz0 = pm ? w2z0 : w1z0;
    const float* bz0 = pm ? b2z0 : b1z0;
    const float* wh0 = pm ? w2h0 : w1h0;
    const float* bh0 = pm ? b2h0 : b1h0;
    const float* wz1 = pm ? w2z1 : w1z1;
    const float* bz1 = pm ? b2z1 : b1z1;
    const float* wh1 = pm ? w2h1 : w1h1;
    const float* bh1 = pm ? b2h1 : b1h1;
    const float* wo  = pm ? w2o  : w1o;
    const float* bov = pm ? b2o  : b1o;

    const int tid  = threadIdx.x;
    const int lane = tid & 63;
    const int tg   = tid >> 6;
    const int q    = lane >> 4;
    const int n    = lane & 15;
    const int seg  = lane & 3;
    const int hidx = (tg << 4) | (lane >> 2);

    __shared__ __align__(16) float s_h[TT * SS];    // h0 of current chunk (swizzled cols)
    __shared__ __align__(16) float s_at[HH * SS];   // layer-1 a-gate [h][t] (swizzled blocks)
    __shared__ __align__(16) float s_bt[HH * SS];   // layer-1 b-gate [h][t] (swizzled blocks)
    __shared__ float s_p[4 * TT];                   // per-wave output partials

    const float* xrow = x + (size_t)b * LL;

    // ---- layer-0 LUT per hidx (x is bernoulli {0,1}) ----
    const float z0v = sigmoidf_(bz0[hidx]);
    const float z1v = sigmoidf_(wz0[hidx] + bz0[hidx]);
    const float a0v = 1.0f - z0v, b0v = z0v * bh0[hidx];
    const float a1v = 1.0f - z1v, b1v = z1v * (wh0[hidx] + bh0[hidx]);

    // ---- layer-1 biases (MFMA n-mapping) ----
    float rbz1[4], rbh1[4];
    #pragma unroll
    for (int ht = 0; ht < 4; ++ht) {
        rbz1[ht] = bz1[ht * 16 + n];
        rbh1[ht] = bh1[ht * 16 + n];
    }
    const float bo   = bov[0];
    const float rwoh = wo[hidx];

    // ---- layer-1 weight B-fragments (hi/lo bf16 split) ----
    bf16x8 wfz_hi[2][4], wfz_lo[2][4], wfh_hi[2][4], wfh_lo[2][4];
    for (int ks = 0; ks < 2; ++ks) {
        for (int ht = 0; ht < 4; ++ht) {
            #pragma unroll
            for (int j = 0; j < 8; ++j) {
                const int kk = ks * 32 + q * 8 + j;
                const int hh = ht * 16 + n;
                const float wz = wz1[kk * HH + hh];
                const short zh = f2bf(wz);
                wfz_hi[ks][ht][j] = zh;
                wfz_lo[ks][ht][j] = f2bf(wz - bf2f(zh));
                const float wh = wh1[kk * HH + hh];
                const short hh2 = f2bf(wh);
                wfh_hi[ks][ht][j] = hh2;
                wfh_lo[ks][ht][j] = f2bf(wh - bf2f(hh2));
            }
        }
    }

    float carry0 = 0.0f, carry1 = 0.0f;
    float lsum = 0.0f, lsum2 = 0.0f;
    float* outp = out + (pm ? 1 : 0);
    const int t0 = tg * 16;
    // s_h column swizzle: stored_col = col ^ (((t>>4)&1)<<4)
    const int col0 = hidx ^ ((seg & 1) << 4);

    float xv[16];

    // ---- prologue: P1(0) ----
    load_x(xrow, p, pm, seg * 16, xv);
    p1_scan(xv, a0v, b0v, a1v, b1v, seg, col0, carry0, s_h);
    __syncthreads();

    for (int c = 0; c < NCH; ++c) {
        const int cp1 = c + 1;

        // ===== group 1: x-prefetch(c+1), P5-final(c-1), P3(c) =====
        if (cp1 < NCH)
            load_x(xrow, p, pm, cp1 * TT + seg * 16, xv);

        if (c > 0 && tid < TT) {   // P5 final for chunk c-1
            const float v = s_p[tid] + s_p[64 + tid] + s_p[128 + tid] + s_p[192 + tid] + bo;
            outp[((size_t)b * LL + (c - 1) * TT + tid) * 2] = v;
            lsum += v;
            lsum2 = fmaf(v, v, lsum2);
        }

        // P3: layer-1 matmuls on MFMA (3-term hi/lo split)
        {
            f32x4 accz[4], acch[4];
            #pragma unroll
            for (int ht = 0; ht < 4; ++ht) {
                accz[ht] = (f32x4){rbz1[ht], rbz1[ht], rbz1[ht], rbz1[ht]};
                acch[ht] = (f32x4){rbh1[ht], rbh1[ht], rbh1[ht], rbh1[ht]};
            }
            const int qs = q ^ ((tg & 1) << 1);   // undo s_h col swizzle (t>>4 == tg)
            #pragma unroll
            for (int ks = 0; ks < 2; ++ks) {
                const float* ap = &s_h[(t0 + n) * SS + ks * 32 + qs * 8];
                const float4 av0 = *(const float4*)ap;
                const float4 av1 = *(const float4*)(ap + 4);
                float af[8] = {av0.x, av0.y, av0.z, av0.w, av1.x, av1.y, av1.z, av1.w};
                bf16x8 ahi, alo;
                #pragma unroll
                for (int j = 0; j < 8; ++j) {
                    const short h16 = f2bf(af[j]);
                    ahi[j] = h16;
                    alo[j] = f2bf(af[j] - bf2f(h16));
                }
                #pragma unroll
                for (int ht = 0; ht < 4; ++ht) {
                    accz[ht] = __builtin_amdgcn_mfma_f32_16x16x32_bf16(ahi, wfz_hi[ks][ht], accz[ht], 0, 0, 0);
                    accz[ht] = __builtin_amdgcn_mfma_f32_16x16x32_bf16(alo, wfz_hi[ks][ht], accz[ht], 0, 0, 0);
                    accz[ht] = __builtin_amdgcn_mfma_f32_16x16x32_bf16(ahi, wfz_lo[ks][ht], accz[ht], 0, 0, 0);
                    acch[ht] = __builtin_amdgcn_mfma_f32_16x16x32_bf16(ahi, wfh_hi[ks][ht], acch[ht], 0, 0, 0);
                    acch[ht] = __builtin_amdgcn_mfma_f32_16x16x32_bf16(alo, wfh_hi[ks][ht], acch[ht], 0, 0, 0);
                    acch[ht] = __builtin_amdgcn_mfma_f32_16x16x32_bf16(ahi, wfh_lo[ks][ht], acch[ht], 0, 0, 0);
                }
            }
            // epilogue: gates -> s_at/s_bt, [h][t] with float4-block swizzle
            const int cbw = 4 * ((tg * 4 + q) ^ (n & 3));
            #pragma unroll
            for (int ht = 0; ht < 4; ++ht) {
                float4 av, bv4;
                float* avp = (float*)&av; float* bvp = (float*)&bv4;
                #pragma unroll
                for (int r = 0; r < 4; ++r) {
                    const float z = sigmoidf_(accz[ht][r]);
                    avp[r] = 1.0f - z;
                    bvp[r] = z * acch[ht][r];
                }
                const int row = ht * 16 + n;
                *(float4*)&s_at[row * SS + cbw] = av;
                *(float4*)&s_bt[row * SS + cbw] = bv4;
            }
        }
        __syncthreads();   // A: s_at/s_bt ready; s_h now dead

        // ===== group 2: P4(c) scan + output butterfly, P1(c+1) -> s_h =====
        {
            float ai[16], bi[16];
            #pragma unroll
            for (int j4 = 0; j4 < 4; ++j4) {
                const int cb = 4 * ((seg * 4 + j4) ^ (hidx & 3));
                const float4 av = *(const float4*)&s_at[hidx * SS + cb];
                const float4 bv = *(const float4*)&s_bt[hidx * SS + cb];
                ai[4*j4+0] = av.x; ai[4*j4+1] = av.y; ai[4*j4+2] = av.z; ai[4*j4+3] = av.w;
                bi[4*j4+0] = bv.x; bi[4*j4+1] = bv.y; bi[4*j4+2] = bv.z; bi[4*j4+3] = bv.w;
            }
            float A = 1.0f, Bv = 0.0f;
            #pragma unroll
            for (int i = 0; i < 16; ++i) {
                A  = A * ai[i];
                Bv = fmaf(Bv, ai[i], bi[i]);
            }
            {
                const float Au = __shfl_up(A, 1, 4), Bu = __shfl_up(Bv, 1, 4);
                if (seg >= 1) { const float Ac = A; A = Au * Ac; Bv = fmaf(Bu, Ac, Bv); }
                const float Au2 = __shfl_up(A, 2, 4), Bu2 = __shfl_up(Bv, 2, 4);
                if (seg >= 2) { const float Ac = A; A = Au2 * Ac; Bv = fmaf(Bu2, Ac, Bv); }
            }
            float Ae = __shfl_up(A, 1, 4), Be = __shfl_up(Bv, 1, 4);
            if (seg == 0) { Ae = 1.0f; Be = 0.0f; }
            float cc = fmaf(Ae, carry1, Be);
            float pt[16];
            #pragma unroll
            for (int i = 0; i < 16; ++i) {
                cc = fmaf(ai[i], cc, bi[i]);
                pt[i] = cc * rwoh;
            }
            carry1 = __shfl(cc, lane | 3);
            const float r = reduce16_quadgroups(pt, lane >> 2);
            s_p[tg * 64 + seg * 16 + (lane >> 2)] = r;
        }

        if (cp1 < NCH)
            p1_scan(xv, a0v, b0v, a1v, b1v, seg, col0, carry0, s_h);
        __syncthreads();   // B: s_p and s_h(c+1) ready
    }

    // ---- P5 final for last chunk ----
    if (tid < TT) {
        const float v = s_p[tid] + s_p[64 + tid] + s_p[128 + tid] + s_p[192 + tid] + bo;
        outp[((size_t)b * LL + (NCH - 1) * TT + tid) * 2] = v;
        lsum += v;
        lsum2 = fmaf(v, v, lsum2);
    }

    // ---- block partial (only wave 0 holds nonzero) -> ws slots (plain stores) ----
    if (tg == 0) {
        #pragma unroll
        for (int o = 32; o; o >>= 1) {
            lsum  += __shfl_down(lsum, o);
            lsum2 += __shfl_down(lsum2, o);
        }
        if (lane == 0) {
            const int gb = b * 2 + (pm ? 1 : 0);
            ws[2 * gb]     = lsum;
            ws[2 * gb + 1] = lsum2;
        }
    }
}

// Fold the 512 block-partials (redundantly per block), normalize in-place.
__global__ void normalize_k(float* __restrict__ out, const float* __restrict__ ws)
{
    __shared__ float s_red[8];
    float s = 0.0f, s2 = 0.0f;
    for (int i = threadIdx.x; i < 2 * BB; i += 256) {
        s  += ws[2 * i];
        s2 += ws[2 * i + 1];
    }
    #pragma unroll
    for (int o = 32; o; o >>= 1) {
        s  += __shfl_down(s, o);
        s2 += __shfl_down(s2, o);
    }
    const int wid = threadIdx.x >> 6;
    if ((threadIdx.x & 63) == 0) { s_red[wid] = s; s_red[4 + wid] = s2; }
    __syncthreads();
    const float tot  = s_red[0] + s_red[1] + s_red[2] + s_red[3];
    const float tot2 = s_red[4] + s_red[5] + s_red[6] + s_red[7];
    const float N    = (float)NTOT;
    const float mean = tot / N;
    const float var  = (tot2 - N * mean * mean) / (N - 1.0f);
    const float inv  = rsqrtf(var);

    const int i = blockIdx.x * blockDim.x + threadIdx.x;   // exactly NTOT/4 threads
    float4* o4 = (float4*)out;
    float4 v = o4[i];
    v.x = (v.x - mean) * inv;
    v.y = (v.y - mean) * inv;
    v.z = (v.z - mean) * inv;
    v.w = (v.w - mean) * inv;
    o4[i] = v;
}

extern "C" void kernel_launch(void* const* d_in, const int* in_sizes, int n_in,
                              void* d_out, int out_size, void* d_ws, size_t ws_size,
                              hipStream_t stream)
{
    (void)in_sizes; (void)n_in; (void)out_size; (void)ws_size;
    const float* x = (const float*)d_in[0];
    const int*   p = (const int*)d_in[1];
    float* out = (float*)d_out;
    float* ws  = (float*)d_ws;

    dim3 grid(BB, 2);
    gru_fused<<<grid, 256, 0, stream>>>(
        x, p,
        (const float*)d_in[2],  (const float*)d_in[3],
        (const float*)d_in[4],  (const float*)d_in[5],
        (const float*)d_in[6],  (const float*)d_in[7],
        (const float*)d_in[8],  (const float*)d_in[9],
        (const float*)d_in[10], (const float*)d_in[11],
        (const float*)d_in[12], (const float*)d_in[13],
        (const float*)d_in[14], (const float*)d_in[15],
        (const float*)d_in[16], (const float*)d_in[17],
        (const float*)d_in[18], (const float*)d_in[19],
        (const float*)d_in[20], (const float*)d_in[21],
        out, ws);

    normalize_k<<<NTOT / 4 / 256, 256, 0, stream>>>(out, ws);
}

// Round 6
// 222.064 us; speedup vs baseline: 2.7270x; 1.2502x over previous
//
#include <hip/hip_runtime.h>

#define BB 256
#define LL 2048
#define HH 64
#define TT 64            // chunk length along L
#define SS 68            // padded LDS row stride (floats)
#define NCH (LL / TT)    // 32 chunks
#define NTOT (BB * LL * 2)

typedef __attribute__((ext_vector_type(8))) short bf16x8;
typedef __attribute__((ext_vector_type(4))) float f32x4;

__device__ __forceinline__ float sigmoidf_(float v) {
    return 1.0f / (1.0f + __expf(-v));
}
__device__ __forceinline__ short f2bf(float f) {
    union { float f; unsigned u; } v; v.f = f;
    unsigned r = v.u + 0x7fff + ((v.u >> 16) & 1);
    return (short)(r >> 16);
}
__device__ __forceinline__ float bf2f(short s) {
    union { unsigned u; float f; } v;
    v.u = ((unsigned)(unsigned short)s) << 16;
    return v.f;
}

// DPP quad_perm helper: 1-cycle VALU cross-lane within each quad.
// 0x90 = [0,0,1,2] (shift-up-1), 0x44 = [0,1,0,1] (shift-up-2),
// 0xFF = [3,3,3,3] (broadcast lane 3 of quad).
template<int CTRL>
__device__ __forceinline__ float qdpp(float x) {
    union { float f; int i; } u, r;
    u.f = x;
    r.i = __builtin_amdgcn_update_dpp(0, u.i, CTRL, 0xF, 0xF, false);
    return r.f;
}

// Vectorized x-chunk load: 16 consecutive t starting at tb (tb % 16 == 0).
__device__ __forceinline__ void load_x(const float* __restrict__ xrow,
                                       const int* __restrict__ p,
                                       bool pm, int tb, float* xv)
{
    if (!pm) {
        const float4* x4 = (const float4*)(xrow + tb);
        #pragma unroll
        for (int k = 0; k < 4; ++k) {
            const float4 v = x4[k];
            xv[4*k+0] = v.x; xv[4*k+1] = v.y; xv[4*k+2] = v.z; xv[4*k+3] = v.w;
        }
    } else {
        const int4* p4 = (const int4*)(p + tb);
        int idx[16];
        #pragma unroll
        for (int k = 0; k < 4; ++k) {
            const int4 v = p4[k];
            idx[4*k+0] = v.x; idx[4*k+1] = v.y; idx[4*k+2] = v.z; idx[4*k+3] = v.w;
        }
        #pragma unroll
        for (int i = 0; i < 16; ++i) xv[i] = xrow[idx[i]];
    }
}

// Layer-0 gates from Bernoulli LUT + 64-step scan (16 local + quad scan via DPP),
// writes h0 to sh with the bit4 column swizzle.
__device__ __forceinline__ void p1_scan(const float* xv,
                                        float a0v, float b0v, float a1v, float b1v,
                                        int seg, int col0, float& carry, float* sh)
{
    float ai[16], bi[16];
    float A = 1.0f, Bv = 0.0f;
    #pragma unroll
    for (int i = 0; i < 16; ++i) {
        const bool on = (xv[i] != 0.0f);
        ai[i] = on ? a1v : a0v;
        bi[i] = on ? b1v : b0v;
        A  = A * ai[i];
        Bv = fmaf(Bv, ai[i], bi[i]);
    }
    {
        const float Au = qdpp<0x90>(A), Bu = qdpp<0x90>(Bv);
        if (seg >= 1) { const float Ac = A; A = Au * Ac; Bv = fmaf(Bu, Ac, Bv); }
        const float Au2 = qdpp<0x44>(A), Bu2 = qdpp<0x44>(Bv);
        if (seg >= 2) { const float Ac = A; A = Au2 * Ac; Bv = fmaf(Bu2, Ac, Bv); }
    }
    float Ae = qdpp<0x90>(A), Be = qdpp<0x90>(Bv);
    if (seg == 0) { Ae = 1.0f; Be = 0.0f; }
    float cc = fmaf(Ae, carry, Be);
    #pragma unroll
    for (int i = 0; i < 16; ++i) {
        cc = fmaf(ai[i], cc, bi[i]);
        sh[(seg * 16 + i) * SS + col0] = cc;
    }
    carry = qdpp<0xFF>(cc);   // broadcast quad's lane-3 (seg=3) final state
}

// Distributed butterfly: v[16] per lane; sums index i across the 16 quad-groups
// (lane bits 2-5), preserving lane&3. Lane ends with the full sum for i == lane>>2.
__device__ __forceinline__ float reduce16_quadgroups(const float* v, int m) {
    float a[8];
    #pragma unroll
    for (int k = 0; k < 8; ++k) {
        const float keep = (m & 1) ? v[2*k+1] : v[2*k];
        const float send = (m & 1) ? v[2*k]   : v[2*k+1];
        a[k] = keep + __shfl_xor(send, 4);
    }
    float b2[4];
    #pragma unroll
    for (int k = 0; k < 4; ++k) {
        const float keep = (m & 2) ? a[2*k+1] : a[2*k];
        const float send = (m & 2) ? a[2*k]   : a[2*k+1];
        b2[k] = keep + __shfl_xor(send, 8);
    }
    float c2[2];
    #pragma unroll
    for (int k = 0; k < 2; ++k) {
        const float keep = (m & 4) ? b2[2*k+1] : b2[2*k];
        const float send = (m & 4) ? b2[2*k]   : b2[2*k+1];
        c2[k] = keep + __shfl_xor(send, 16);
    }
    const float keep = (m & 8) ? c2[1] : c2[0];
    const float send = (m & 8) ? c2[0] : c2[1];
    return keep + __shfl_xor(send, 32);
}

__global__ void __launch_bounds__(256)
__attribute__((amdgpu_waves_per_eu(2, 2)))   // pin 2 waves/EU -> 256 VGPR budget, no spill
gru_fused(const float* __restrict__ x, const int* __restrict__ p,
               const float* __restrict__ w1z0, const float* __restrict__ b1z0,
               const float* __restrict__ w1h0, const float* __restrict__ b1h0,
               const float* __restrict__ w1z1, const float* __restrict__ b1z1,
               const float* __restrict__ w1h1, const float* __restrict__ b1h1,
               const float* __restrict__ w1o,  const float* __restrict__ b1o,
               const float* __restrict__ w2z0, const float* __restrict__ b2z0,
               const float* __restrict__ w2h0, const float* __restrict__ b2h0,
               const float* __restrict__ w2z1, const float* __restrict__ b2z1,
               const float* __restrict__ w2h1, const float* __restrict__ b2h1,
               const float* __restrict__ w2o,  const float* __restrict__ b2o,
               float* __restrict__ out, float* __restrict__ ws)
{
    const int  b  = blockIdx.x;
    const bool pm = (blockIdx.y != 0);

    const float* wz0 = pm ? w2z0 : w1z0;
    const float* bz0 = pm ? b2z0 : b1z0;
    const float* wh0 = pm ? w2h0 : w1h0;
    const float* bh0 = pm ? b2h0 : b1h0;
    const float* wz1 = pm ? w2z1 : w1z1;
    const float* bz1 = pm ? b2z1 : b1z1;
    const float* wh1 = pm ? w2h1 : w1h1;
    const float* bh1 = pm ? b2h1 : b1h1;
    const float* wo  = pm ? w2o  : w1o;
    const float* bov = pm ? b2o  : b1o;

    const int tid  = threadIdx.x;
    const int lane = tid & 63;
    const int tg   = tid >> 6;
    const int q    = lane >> 4;
    const int n    = lane & 15;
    const int seg  = lane & 3;
    const int hidx = (tg << 4) | (lane >> 2);

    __shared__ __align__(16) float s_h[TT * SS];    // h0 of current chunk (swizzled cols)
    __shared__ __align__(16) float s_at[HH * SS];   // layer-1 a-gate [h][t] (swizzled blocks)
    __shared__ __align__(16) float s_bt[HH * SS];   // layer-1 b-gate [h][t] (swizzled blocks)
    __shared__ float s_p[4 * TT];                   // per-wave output partials

    const float* xrow = x + (size_t)b * LL;

    // ---- layer-0 LUT per hidx (x is bernoulli {0,1}) ----
    const float z0v = sigmoidf_(bz0[hidx]);
    const float z1v = sigmoidf_(wz0[hidx] + bz0[hidx]);
    const float a0v = 1.0f - z0v, b0v = z0v * bh0[hidx];
    const float a1v = 1.0f - z1v, b1v = z1v * (wh0[hidx] + bh0[hidx]);

    // ---- layer-1 biases (MFMA n-mapping) ----
    float rbz1[4], rbh1[4];
    #pragma unroll
    for (int ht = 0; ht < 4; ++ht) {
        rbz1[ht] = bz1[ht * 16 + n];
        rbh1[ht] = bh1[ht * 16 + n];
    }
    const float bo   = bov[0];
    const float rwoh = wo[hidx];

    // ---- layer-1 weight B-fragments, hi only (2-term split: err ~2^-9 |W|) ----
    bf16x8 wfz_hi[2][4], wfh_hi[2][4];
    for (int ks = 0; ks < 2; ++ks) {
        for (int ht = 0; ht < 4; ++ht) {
            #pragma unroll
            for (int j = 0; j < 8; ++j) {
                const int kk = ks * 32 + q * 8 + j;
                const int hh = ht * 16 + n;
                wfz_hi[ks][ht][j] = f2bf(wz1[kk * HH + hh]);
                wfh_hi[ks][ht][j] = f2bf(wh1[kk * HH + hh]);
            }
        }
    }

    float carry0 = 0.0f, carry1 = 0.0f;
    float lsum = 0.0f, lsum2 = 0.0f;
    float* outp = out + (pm ? 1 : 0);
    const int t0 = tg * 16;
    // s_h column swizzle: stored_col = col ^ (((t>>4)&1)<<4)
    const int col0 = hidx ^ ((seg & 1) << 4);

    float xv[16];

    // ---- prologue: P1(0) ----
    load_x(xrow, p, pm, seg * 16, xv);
    p1_scan(xv, a0v, b0v, a1v, b1v, seg, col0, carry0, s_h);
    __syncthreads();

    for (int c = 0; c < NCH; ++c) {
        const int cp1 = c + 1;

        // ===== group 1: x-prefetch(c+1), P5-final(c-1), P3(c) =====
        if (cp1 < NCH)
            load_x(xrow, p, pm, cp1 * TT + seg * 16, xv);

        if (c > 0 && tid < TT) {   // P5 final for chunk c-1
            const float v = s_p[tid] + s_p[64 + tid] + s_p[128 + tid] + s_p[192 + tid] + bo;
            outp[((size_t)b * LL + (c - 1) * TT + tid) * 2] = v;
            lsum += v;
            lsum2 = fmaf(v, v, lsum2);
        }

        // P3: layer-1 matmuls on MFMA (2-term A-hi/lo x B-hi)
        {
            f32x4 accz[4], acch[4];
            #pragma unroll
            for (int ht = 0; ht < 4; ++ht) {
                accz[ht] = (f32x4){rbz1[ht], rbz1[ht], rbz1[ht], rbz1[ht]};
                acch[ht] = (f32x4){rbh1[ht], rbh1[ht], rbh1[ht], rbh1[ht]};
            }
            const int qs = q ^ ((tg & 1) << 1);   // undo s_h col swizzle (t>>4 == tg)
            #pragma unroll
            for (int ks = 0; ks < 2; ++ks) {
                const float* ap = &s_h[(t0 + n) * SS + ks * 32 + qs * 8];
                const float4 av0 = *(const float4*)ap;
                const float4 av1 = *(const float4*)(ap + 4);
                float af[8] = {av0.x, av0.y, av0.z, av0.w, av1.x, av1.y, av1.z, av1.w};
                bf16x8 ahi, alo;
                #pragma unroll
                for (int j = 0; j < 8; ++j) {
                    const short h16 = f2bf(af[j]);
                    ahi[j] = h16;
                    alo[j] = f2bf(af[j] - bf2f(h16));
                }
                #pragma unroll
                for (int ht = 0; ht < 4; ++ht) {
                    accz[ht] = __builtin_amdgcn_mfma_f32_16x16x32_bf16(ahi, wfz_hi[ks][ht], accz[ht], 0, 0, 0);
                    accz[ht] = __builtin_amdgcn_mfma_f32_16x16x32_bf16(alo, wfz_hi[ks][ht], accz[ht], 0, 0, 0);
                    acch[ht] = __builtin_amdgcn_mfma_f32_16x16x32_bf16(ahi, wfh_hi[ks][ht], acch[ht], 0, 0, 0);
                    acch[ht] = __builtin_amdgcn_mfma_f32_16x16x32_bf16(alo, wfh_hi[ks][ht], acch[ht], 0, 0, 0);
                }
            }
            // epilogue: gates -> s_at/s_bt, [h][t] with float4-block swizzle
            const int cbw = 4 * ((tg * 4 + q) ^ (n & 3));
            #pragma unroll
            for (int ht = 0; ht < 4; ++ht) {
                float4 av, bv4;
                float* avp = (float*)&av; float* bvp = (float*)&bv4;
                #pragma unroll
                for (int r = 0; r < 4; ++r) {
                    const float z = sigmoidf_(accz[ht][r]);
                    avp[r] = 1.0f - z;
                    bvp[r] = z * acch[ht][r];
                }
                const int row = ht * 16 + n;
                *(float4*)&s_at[row * SS + cbw] = av;
                *(float4*)&s_bt[row * SS + cbw] = bv4;
            }
        }
        __syncthreads();   // A: s_at/s_bt ready; s_h now dead

        // ===== group 2: P4(c) scan + output butterfly, P1(c+1) -> s_h =====
        {
            float ai[16], bi[16];
            #pragma unroll
            for (int j4 = 0; j4 < 4; ++j4) {
                const int cb = 4 * ((seg * 4 + j4) ^ (hidx & 3));
                const float4 av = *(const float4*)&s_at[hidx * SS + cb];
                const float4 bv = *(const float4*)&s_bt[hidx * SS + cb];
                ai[4*j4+0] = av.x; ai[4*j4+1] = av.y; ai[4*j4+2] = av.z; ai[4*j4+3] = av.w;
                bi[4*j4+0] = bv.x; bi[4*j4+1] = bv.y; bi[4*j4+2] = bv.z; bi[4*j4+3] = bv.w;
            }
            float A = 1.0f, Bv = 0.0f;
            #pragma unroll
            for (int i = 0; i < 16; ++i) {
                A  = A * ai[i];
                Bv = fmaf(Bv, ai[i], bi[i]);
            }
            {
                const float Au = qdpp<0x90>(A), Bu = qdpp<0x90>(Bv);
                if (seg >= 1) { const float Ac = A; A = Au * Ac; Bv = fmaf(Bu, Ac, Bv); }
                const float Au2 = qdpp<0x44>(A), Bu2 = qdpp<0x44>(Bv);
                if (seg >= 2) { const float Ac = A; A = Au2 * Ac; Bv = fmaf(Bu2, Ac, Bv); }
            }
            float Ae = qdpp<0x90>(A), Be = qdpp<0x90>(Bv);
            if (seg == 0) { Ae = 1.0f; Be = 0.0f; }
            float cc = fmaf(Ae, carry1, Be);
            float pt[16];
            #pragma unroll
            for (int i = 0; i < 16; ++i) {
                cc = fmaf(ai[i], cc, bi[i]);
                pt[i] = cc * rwoh;
            }
            carry1 = qdpp<0xFF>(cc);
            const float r = reduce16_quadgroups(pt, lane >> 2);
            s_p[tg * 64 + seg * 16 + (lane >> 2)] = r;
        }

        if (cp1 < NCH)
            p1_scan(xv, a0v, b0v, a1v, b1v, seg, col0, carry0, s_h);
        __syncthreads();   // B: s_p and s_h(c+1) ready
    }

    // ---- P5 final for last chunk ----
    if (tid < TT) {
        const float v = s_p[tid] + s_p[64 + tid] + s_p[128 + tid] + s_p[192 + tid] + bo;
        outp[((size_t)b * LL + (NCH - 1) * TT + tid) * 2] = v;
        lsum += v;
        lsum2 = fmaf(v, v, lsum2);
    }

    // ---- block partial (only wave 0 holds nonzero) -> ws slots (plain stores) ----
    if (tg == 0) {
        #pragma unroll
        for (int o = 32; o; o >>= 1) {
            lsum  += __shfl_down(lsum, o);
            lsum2 += __shfl_down(lsum2, o);
        }
        if (lane == 0) {
            const int gb = b * 2 + (pm ? 1 : 0);
            ws[2 * gb]     = lsum;
            ws[2 * gb + 1] = lsum2;
        }
    }
}

// Fold the 512 block-partials (redundantly per block), normalize in-place.
__global__ void normalize_k(float* __restrict__ out, const float* __restrict__ ws)
{
    __shared__ float s_red[8];
    float s = 0.0f, s2 = 0.0f;
    for (int i = threadIdx.x; i < 2 * BB; i += 256) {
        s  += ws[2 * i];
        s2 += ws[2 * i + 1];
    }
    #pragma unroll
    for (int o = 32; o; o >>= 1) {
        s  += __shfl_down(s, o);
        s2 += __shfl_down(s2, o);
    }
    const int wid = threadIdx.x >> 6;
    if ((threadIdx.x & 63) == 0) { s_red[wid] = s; s_red[4 + wid] = s2; }
    __syncthreads();
    const float tot  = s_red[0] + s_red[1] + s_red[2] + s_red[3];
    const float tot2 = s_red[4] + s_red[5] + s_red[6] + s_red[7];
    const float N    = (float)NTOT;
    const float mean = tot / N;
    const float var  = (tot2 - N * mean * mean) / (N - 1.0f);
    const float inv  = rsqrtf(var);

    const int i = blockIdx.x * blockDim.x + threadIdx.x;   // exactly NTOT/4 threads
    float4* o4 = (float4*)out;
    float4 v = o4[i];
    v.x = (v.x - mean) * inv;
    v.y = (v.y - mean) * inv;
    v.z = (v.z - mean) * inv;
    v.w = (v.w - mean) * inv;
    o4[i] = v;
}

extern "C" void kernel_launch(void* const* d_in, const int* in_sizes, int n_in,
                              void* d_out, int out_size, void* d_ws, size_t ws_size,
                              hipStream_t stream)
{
    (void)in_sizes; (void)n_in; (void)out_size; (void)ws_size;
    const float* x = (const float*)d_in[0];
    const int*   p = (const int*)d_in[1];
    float* out = (float*)d_out;
    float* ws  = (float*)d_ws;

    dim3 grid(BB, 2);
    gru_fused<<<grid, 256, 0, stream>>>(
        x, p,
        (const float*)d_in[2],  (const float*)d_in[3],
        (const float*)d_in[4],  (const float*)d_in[5],
        (const float*)d_in[6],  (const float*)d_in[7],
        (const float*)d_in[8],  (const float*)d_in[9],
        (const float*)d_in[10], (const float*)d_in[11],
        (const float*)d_in[12], (const float*)d_in[13],
        (const float*)d_in[14], (const float*)d_in[15],
        (const float*)d_in[16], (const float*)d_in[17],
        (const float*)d_in[18], (const float*)d_in[19],
        (const float*)d_in[20], (const float*)d_in[21],
        out, ws);

    normalize_k<<<NTOT / 4 / 256, 256, 0, stream>>>(out, ws);
}

// Round 7
// 212.585 us; speedup vs baseline: 2.8485x; 1.0446x over previous
//
#include <hip/hip_runtime.h>

#define BB 256
#define LL 2048
#define HH 64
#define TT 64            // chunk length along L
#define SS 68            // padded LDS row stride (floats)
#define NCH (LL / TT)    // 32 chunks
#define NTOT (BB * LL * 2)

typedef __attribute__((ext_vector_type(8))) short bf16x8;
typedef __attribute__((ext_vector_type(4))) float f32x4;

__device__ __forceinline__ float rcp_(float x) { return __builtin_amdgcn_rcpf(x); }

// RNE fp32->bf16 (weights only, outside hot loop)
__device__ __forceinline__ short f2bf_rne(float f) {
    union { float f; unsigned u; } v; v.f = f;
    unsigned r = v.u + 0x7fff + ((v.u >> 16) & 1);
    return (short)(r >> 16);
}

// DPP quad_perm: 0x90 = shift-up-1, 0x44 = shift-up-2, 0xFF = bcast lane3 of quad.
template<int CTRL>
__device__ __forceinline__ float qdpp(float x) {
    union { float f; int i; } u, r;
    u.f = x;
    r.i = __builtin_amdgcn_update_dpp(0, u.i, CTRL, 0xF, 0xF, false);
    return r.f;
}

// Vectorized x-chunk load: 16 consecutive t starting at tb (tb % 16 == 0).
__device__ __forceinline__ void load_x(const float* __restrict__ xrow,
                                       const int* __restrict__ p,
                                       bool pm, int tb, float* xv)
{
    if (!pm) {
        const float4* x4 = (const float4*)(xrow + tb);
        #pragma unroll
        for (int k = 0; k < 4; ++k) {
            const float4 v = x4[k];
            xv[4*k+0] = v.x; xv[4*k+1] = v.y; xv[4*k+2] = v.z; xv[4*k+3] = v.w;
        }
    } else {
        const int4* p4 = (const int4*)(p + tb);
        int idx[16];
        #pragma unroll
        for (int k = 0; k < 4; ++k) {
            const int4 v = p4[k];
            idx[4*k+0] = v.x; idx[4*k+1] = v.y; idx[4*k+2] = v.z; idx[4*k+3] = v.w;
        }
        #pragma unroll
        for (int i = 0; i < 16; ++i) xv[i] = xrow[idx[i]];
    }
}

// Layer-0 gates (Bernoulli LUT) + 64-step scan (16 local + quad scan via DPP),
// writes h0 to sh with the bit4 column swizzle.
__device__ __forceinline__ void p1_scan(const float* xv,
                                        float a0v, float b0v, float a1v, float b1v,
                                        int seg, int col0, float& carry, float* sh)
{
    float ai[16], bi[16];
    float A = 1.0f, Bv = 0.0f;
    #pragma unroll
    for (int i = 0; i < 16; ++i) {
        const bool on = (xv[i] != 0.0f);
        ai[i] = on ? a1v : a0v;
        bi[i] = on ? b1v : b0v;
        A  = A * ai[i];
        Bv = fmaf(Bv, ai[i], bi[i]);
    }
    {
        const float Au = qdpp<0x90>(A), Bu = qdpp<0x90>(Bv);
        if (seg >= 1) { const float Ac = A; A = Au * Ac; Bv = fmaf(Bu, Ac, Bv); }
        const float Au2 = qdpp<0x44>(A), Bu2 = qdpp<0x44>(Bv);
        if (seg >= 2) { const float Ac = A; A = Au2 * Ac; Bv = fmaf(Bu2, Ac, Bv); }
    }
    float Ae = qdpp<0x90>(A), Be = qdpp<0x90>(Bv);
    if (seg == 0) { Ae = 1.0f; Be = 0.0f; }
    float cc = fmaf(Ae, carry, Be);
    #pragma unroll
    for (int i = 0; i < 16; ++i) {
        cc = fmaf(ai[i], cc, bi[i]);
        sh[(seg * 16 + i) * SS + col0] = cc;
    }
    carry = qdpp<0xFF>(cc);   // broadcast quad lane-3 (seg=3) final state
}

__global__ void __launch_bounds__(256)
__attribute__((amdgpu_waves_per_eu(2, 2)))   // 2 waves/EU -> 256 VGPR budget, no spill
gru_fused(const float* __restrict__ x, const int* __restrict__ p,
               const float* __restrict__ w1z0, const float* __restrict__ b1z0,
               const float* __restrict__ w1h0, const float* __restrict__ b1h0,
               const float* __restrict__ w1z1, const float* __restrict__ b1z1,
               const float* __restrict__ w1h1, const float* __restrict__ b1h1,
               const float* __restrict__ w1o,  const float* __restrict__ b1o,
               const float* __restrict__ w2z0, const float* __restrict__ b2z0,
               const float* __restrict__ w2h0, const float* __restrict__ b2h0,
               const float* __restrict__ w2z1, const float* __restrict__ b2z1,
               const float* __restrict__ w2h1, const float* __restrict__ b2h1,
               const float* __restrict__ w2o,  const float* __restrict__ b2o,
               float* __restrict__ out, float* __restrict__ ws)
{
    const int  b  = blockIdx.x;
    const bool pm = (blockIdx.y != 0);

    const float* wz0 = pm ? w2z0 : w1z0;
    const float* bz0 = pm ? b2z0 : b1z0;
    const float* wh0 = pm ? w2h0 : w1h0;
    const float* bh0 = pm ? b2h0 : b1h0;
    const float* wz1 = pm ? w2z1 : w1z1;
    const float* bz1 = pm ? b2z1 : b1z1;
    const float* wh1 = pm ? w2h1 : w1h1;
    const float* bh1 = pm ? b2h1 : b1h1;
    const float* wo  = pm ? w2o  : w1o;
    const float* bov = pm ? b2o  : b1o;

    const int tid  = threadIdx.x;
    const int lane = tid & 63;
    const int tg   = tid >> 6;          // wave id; owns t-block [16*tg, 16*tg+16)
    const int q    = lane >> 4;         // MFMA quad (t sub-block)
    const int n    = lane & 15;         // MFMA col (h low bits)
    const int seg  = lane & 3;          // P1 segment
    const int hidx = (tg << 4) | (lane >> 2);

    __shared__ __align__(16) float s_h[2 * TT * SS];   // double-buffered h0 (swizzled cols)
    __shared__ float2 s_w[2][4][HH];                   // per-wave-block scan transforms (A,B)
    __shared__ float s_red[8];

    const float* xrow = x + (size_t)b * LL;

    // ---- layer-0 LUT per hidx (x is bernoulli {0,1}) ----
    const float z0v = rcp_(1.0f + __expf(-bz0[hidx]));
    const float z1v = rcp_(1.0f + __expf(-(wz0[hidx] + bz0[hidx])));
    const float a0v = 1.0f - z0v, b0v = z0v * bh0[hidx];
    const float a1v = 1.0f - z1v, b1v = z1v * (wh0[hidx] + bh0[hidx]);

    // ---- layer-1 biases + output weights (MFMA (ht,n) mapping) ----
    float rbz1[4], rbh1[4], rwo4[4];
    #pragma unroll
    for (int ht = 0; ht < 4; ++ht) {
        rbz1[ht] = bz1[ht * 16 + n];
        rbh1[ht] = bh1[ht * 16 + n];
        rwo4[ht] = wo[ht * 16 + n];
    }
    const float bo = bov[0];

    // ---- layer-1 weight B-fragments, RNE hi only ----
    bf16x8 wfz[2][4], wfh[2][4];
    for (int ks = 0; ks < 2; ++ks) {
        for (int ht = 0; ht < 4; ++ht) {
            #pragma unroll
            for (int j = 0; j < 8; ++j) {
                const int kk = ks * 32 + q * 8 + j;
                const int hh = ht * 16 + n;
                wfz[ks][ht][j] = f2bf_rne(wz1[kk * HH + hh]);
                wfh[ks][ht][j] = f2bf_rne(wh1[kk * HH + hh]);
            }
        }
    }

    float carry0 = 0.0f;
    float carry1[4] = {0.0f, 0.0f, 0.0f, 0.0f};   // per ht (h = ht*16+n)
    f32x4 ga[4], gb[4];                            // layer-1 gates (a,b), chunk-persistent
    float Aqe[4], Bqe[4];                          // exclusive-q transforms, chunk-persistent
    float lsum = 0.0f, lsum2 = 0.0f;
    float* outp = out + (pm ? 1 : 0);
    const int t0 = tg * 16;
    const int col0 = hidx ^ ((seg & 1) << 4);      // s_h col swizzle (write side)

    float xv[16];

    // G2: apply layer-1 scan for chunk cm (gates/Aqe of cm live in registers),
    // fused output projection + store.
    auto g2_step = [&](int cm) {
        const int buf = cm & 1;
        float Acm[4] = {1,1,1,1}, Bcm[4] = {0,0,0,0};
        float Ap[4], Bp[4];
        #pragma unroll
        for (int w = 0; w < 4; ++w) {
            #pragma unroll
            for (int ht = 0; ht < 4; ++ht) {
                if (w == tg) { Ap[ht] = Acm[ht]; Bp[ht] = Bcm[ht]; }
                const float2 ab = s_w[buf][w][ht * 16 + n];
                Bcm[ht] = fmaf(ab.x, Bcm[ht], ab.y);
                Acm[ht] *= ab.x;
            }
        }
        float vo[4] = {0,0,0,0};
        #pragma unroll
        for (int ht = 0; ht < 4; ++ht) {
            float cc = fmaf(Aqe[ht], fmaf(Ap[ht], carry1[ht], Bp[ht]), Bqe[ht]);
            #pragma unroll
            for (int r = 0; r < 4; ++r) {
                cc = fmaf(ga[ht][r], cc, gb[ht][r]);
                vo[r] = fmaf(cc, rwo4[ht], vo[r]);
            }
            carry1[ht] = fmaf(Acm[ht], carry1[ht], Bcm[ht]);
        }
        #pragma unroll
        for (int m = 1; m <= 8; m <<= 1) {
            #pragma unroll
            for (int r = 0; r < 4; ++r) vo[r] += __shfl_xor(vo[r], m);
        }
        if (n == 0) {
            #pragma unroll
            for (int r = 0; r < 4; ++r) {
                const float v = vo[r] + bo;
                outp[((size_t)b * LL + cm * TT + t0 + q * 4 + r) * 2] = v;
                lsum += v;
                lsum2 = fmaf(v, v, lsum2);
            }
        }
    };

    // ---- prologue: P1(0) -> s_h buf 0 ----
    load_x(xrow, p, pm, seg * 16, xv);
    p1_scan(xv, a0v, b0v, a1v, b1v, seg, col0, carry0, s_h);
    __syncthreads();

    for (int c = 0; c < NCH; ++c) {
        const int cp1 = c + 1;

        if (cp1 < NCH)
            load_x(xrow, p, pm, cp1 * TT + seg * 16, xv);

        // ---- G2(c-1): uses previous chunk's gates (still in registers) ----
        if (c > 0) g2_step(c - 1);

        // ---- G1(c): MFMA + gates + per-wave scan transforms ----
        {
            #pragma unroll
            for (int ht = 0; ht < 4; ++ht) {
                ga[ht] = (f32x4){rbz1[ht], rbz1[ht], rbz1[ht], rbz1[ht]};
                gb[ht] = (f32x4){rbh1[ht], rbh1[ht], rbh1[ht], rbh1[ht]};
            }
            const float* shR = s_h + (c & 1) * (TT * SS);
            const int qs = q ^ ((tg & 1) << 1);   // undo s_h col swizzle (t>>4 == tg)
            #pragma unroll
            for (int ks = 0; ks < 2; ++ks) {
                const float* ap = &shR[(t0 + n) * SS + ks * 32 + qs * 8];
                const float4 av0 = *(const float4*)ap;
                const float4 av1 = *(const float4*)(ap + 4);
                float af[8] = {av0.x, av0.y, av0.z, av0.w, av1.x, av1.y, av1.z, av1.w};
                bf16x8 ahi, alo;
                #pragma unroll
                for (int j = 0; j < 8; ++j) {
                    union { float f; unsigned u; } uf; uf.f = af[j];
                    ahi[j] = (short)(uf.u >> 16);                       // truncate
                    union { unsigned u; float f; } hf; hf.u = uf.u & 0xffff0000u;
                    const float rem = af[j] - hf.f;                     // exact
                    union { float f; unsigned u; } ur; ur.f = rem;
                    alo[j] = (short)(ur.u >> 16);
                }
                #pragma unroll
                for (int ht = 0; ht < 4; ++ht) {
                    ga[ht] = __builtin_amdgcn_mfma_f32_16x16x32_bf16(ahi, wfz[ks][ht], ga[ht], 0, 0, 0);
                    ga[ht] = __builtin_amdgcn_mfma_f32_16x16x32_bf16(alo, wfz[ks][ht], ga[ht], 0, 0, 0);
                    gb[ht] = __builtin_amdgcn_mfma_f32_16x16x32_bf16(ahi, wfh[ks][ht], gb[ht], 0, 0, 0);
                    gb[ht] = __builtin_amdgcn_mfma_f32_16x16x32_bf16(alo, wfh[ks][ht], gb[ht], 0, 0, 0);
                }
            }
            // sigmoid -> gates in place: a = e*r1, b = r1*htl, e = exp(-v), r1 = 1/(1+e)
            #pragma unroll
            for (int ht = 0; ht < 4; ++ht) {
                #pragma unroll
                for (int r = 0; r < 4; ++r) {
                    const float v  = ga[ht][r];
                    const float e  = __expf(-v);
                    const float r1 = rcp_(1.0f + e);
                    ga[ht][r] = e * r1;
                    gb[ht][r] = r1 * gb[ht][r];
                }
            }
            // compose own 4 r-steps per ht
            float Aq[4], Bq[4];
            #pragma unroll
            for (int ht = 0; ht < 4; ++ht) {
                float A = 1.0f, B = 0.0f;
                #pragma unroll
                for (int r = 0; r < 4; ++r) {
                    B = fmaf(ga[ht][r], B, gb[ht][r]);
                    A = A * ga[ht][r];
                }
                Aq[ht] = A; Bq[ht] = B;
            }
            // inclusive Hillis-Steele over q (strides 16, 32 lanes)
            #pragma unroll
            for (int ht = 0; ht < 4; ++ht) {
                const float Au = __shfl_up(Aq[ht], 16), Bu = __shfl_up(Bq[ht], 16);
                if (q >= 1) { const float Ac = Aq[ht]; Aq[ht] = Ac * Au; Bq[ht] = fmaf(Ac, Bu, Bq[ht]); }
            }
            #pragma unroll
            for (int ht = 0; ht < 4; ++ht) {
                const float Au = __shfl_up(Aq[ht], 32), Bu = __shfl_up(Bq[ht], 32);
                if (q >= 2) { const float Ac = Aq[ht]; Aq[ht] = Ac * Au; Bq[ht] = fmaf(Ac, Bu, Bq[ht]); }
            }
            // exclusive-q transforms (persist to G2)
            #pragma unroll
            for (int ht = 0; ht < 4; ++ht) {
                const float Ae = __shfl_up(Aq[ht], 16), Be = __shfl_up(Bq[ht], 16);
                Aqe[ht] = (q == 0) ? 1.0f : Ae;
                Bqe[ht] = (q == 0) ? 0.0f : Be;
            }
            // q==3 lanes publish the wave-block inclusive transform
            if (q == 3) {
                #pragma unroll
                for (int ht = 0; ht < 4; ++ht)
                    s_w[c & 1][tg][ht * 16 + n] = make_float2(Aq[ht], Bq[ht]);
            }
        }

        // ---- P1(c+1) -> other s_h buffer ----
        if (cp1 < NCH)
            p1_scan(xv, a0v, b0v, a1v, b1v, seg, col0, carry0,
                    s_h + (cp1 & 1) * (TT * SS));

        __syncthreads();
    }

    // ---- G2 for the last chunk ----
    g2_step(NCH - 1);

    // ---- block partial (sum, sumsq) -> ws slots (plain stores) ----
    #pragma unroll
    for (int o = 32; o; o >>= 1) {
        lsum  += __shfl_down(lsum, o);
        lsum2 += __shfl_down(lsum2, o);
    }
    if (lane == 0) { s_red[tg] = lsum; s_red[4 + tg] = lsum2; }
    __syncthreads();
    if (tid == 0) {
        const int gb2 = b * 2 + (pm ? 1 : 0);
        ws[2 * gb2]     = s_red[0] + s_red[1] + s_red[2] + s_red[3];
        ws[2 * gb2 + 1] = s_red[4] + s_red[5] + s_red[6] + s_red[7];
    }
}

// Fold the 512 block-partials (redundantly per block), normalize in-place.
__global__ void normalize_k(float* __restrict__ out, const float* __restrict__ ws)
{
    __shared__ float s_red[8];
    float s = 0.0f, s2 = 0.0f;
    for (int i = threadIdx.x; i < 2 * BB; i += 256) {
        s  += ws[2 * i];
        s2 += ws[2 * i + 1];
    }
    #pragma unroll
    for (int o = 32; o; o >>= 1) {
        s  += __shfl_down(s, o);
        s2 += __shfl_down(s2, o);
    }
    const int wid = threadIdx.x >> 6;
    if ((threadIdx.x & 63) == 0) { s_red[wid] = s; s_red[4 + wid] = s2; }
    __syncthreads();
    const float tot  = s_red[0] + s_red[1] + s_red[2] + s_red[3];
    const float tot2 = s_red[4] + s_red[5] + s_red[6] + s_red[7];
    const float N    = (float)NTOT;
    const float mean = tot / N;
    const float var  = (tot2 - N * mean * mean) / (N - 1.0f);
    const float inv  = rsqrtf(var);

    const int i = blockIdx.x * blockDim.x + threadIdx.x;   // exactly NTOT/4 threads
    float4* o4 = (float4*)out;
    float4 v = o4[i];
    v.x = (v.x - mean) * inv;
    v.y = (v.y - mean) * inv;
    v.z = (v.z - mean) * inv;
    v.w = (v.w - mean) * inv;
    o4[i] = v;
}

extern "C" void kernel_launch(void* const* d_in, const int* in_sizes, int n_in,
                              void* d_out, int out_size, void* d_ws, size_t ws_size,
                              hipStream_t stream)
{
    (void)in_sizes; (void)n_in; (void)out_size; (void)ws_size;
    const float* x = (const float*)d_in[0];
    const int*   p = (const int*)d_in[1];
    float* out = (float*)d_out;
    float* ws  = (float*)d_ws;

    dim3 grid(BB, 2);
    gru_fused<<<grid, 256, 0, stream>>>(
        x, p,
        (const float*)d_in[2],  (const float*)d_in[3],
        (const float*)d_in[4],  (const float*)d_in[5],
        (const float*)d_in[6],  (const float*)d_in[7],
        (const float*)d_in[8],  (const float*)d_in[9],
        (const float*)d_in[10], (const float*)d_in[11],
        (const float*)d_in[12], (const float*)d_in[13],
        (const float*)d_in[14], (const float*)d_in[15],
        (const float*)d_in[16], (const float*)d_in[17],
        (const float*)d_in[18], (const float*)d_in[19],
        (const float*)d_in[20], (const float*)d_in[21],
        out, ws);

    normalize_k<<<NTOT / 4 / 256, 256, 0, stream>>>(out, ws);
}

// Round 8
// 185.545 us; speedup vs baseline: 3.2637x; 1.1457x over previous
//
#include <hip/hip_runtime.h>

#define BB 256
#define LL 2048
#define HH 64
#define TT 64            // chunk length along L
#define SS 68            // padded LDS row stride (floats)
#define NCH (LL / TT)    // 32 chunks
#define NTOT (BB * LL * 2)

typedef __attribute__((ext_vector_type(8))) short bf16x8;
typedef __attribute__((ext_vector_type(4))) float f32x4;

__device__ __forceinline__ float rcp_(float x) { return __builtin_amdgcn_rcpf(x); }

// RNE fp32->bf16 (weights only, outside hot loop)
__device__ __forceinline__ short f2bf_rne(float f) {
    union { float f; unsigned u; } v; v.f = f;
    unsigned r = v.u + 0x7fff + ((v.u >> 16) & 1);
    return (short)(r >> 16);
}

// DPP quad_perm: 0x90 = shift-up-1, 0x44 = shift-up-2, 0xFF = bcast lane3 of quad.
template<int CTRL>
__device__ __forceinline__ float qdpp(float x) {
    union { float f; int i; } u, r;
    u.f = x;
    r.i = __builtin_amdgcn_update_dpp(0, u.i, CTRL, 0xF, 0xF, false);
    return r.f;
}

// DPP row_shr:D with zero bound: lane i receives lane i-D within its 16-lane row
// (0 shifted in). Used for shift-reduce; lane 15 of each row ends with the row sum.
template<int D>
__device__ __forceinline__ float rshr(float x) {
    union { float f; int i; } u, r;
    u.f = x;
    r.i = __builtin_amdgcn_update_dpp(0, u.i, 0x110 | D, 0xF, 0xF, true);
    return r.f;
}

// Layer-0 gates (Bernoulli LUT) + 64-step scan (16 local + quad scan via DPP),
// reads x from LDS stage, writes h0 to sh with the bit4 column swizzle.
__device__ __forceinline__ void p1_scan(const float* __restrict__ sxp,
                                        float a0v, float b0v, float a1v, float b1v,
                                        int seg, int col0, float& carry, float* sh)
{
    float xi[16];
    #pragma unroll
    for (int k = 0; k < 4; ++k) {
        const float4 v = *(const float4*)(sxp + 4 * k);
        xi[4*k+0] = v.x; xi[4*k+1] = v.y; xi[4*k+2] = v.z; xi[4*k+3] = v.w;
    }
    float ai[16], bi[16];
    float A = 1.0f, Bv = 0.0f;
    #pragma unroll
    for (int i = 0; i < 16; ++i) {
        const bool on = (xi[i] != 0.0f);
        ai[i] = on ? a1v : a0v;
        bi[i] = on ? b1v : b0v;
        A  = A * ai[i];
        Bv = fmaf(Bv, ai[i], bi[i]);
    }
    {
        const float Au = qdpp<0x90>(A), Bu = qdpp<0x90>(Bv);
        if (seg >= 1) { const float Ac = A; A = Au * Ac; Bv = fmaf(Bu, Ac, Bv); }
        const float Au2 = qdpp<0x44>(A), Bu2 = qdpp<0x44>(Bv);
        if (seg >= 2) { const float Ac = A; A = Au2 * Ac; Bv = fmaf(Bu2, Ac, Bv); }
    }
    float Ae = qdpp<0x90>(A), Be = qdpp<0x90>(Bv);
    if (seg == 0) { Ae = 1.0f; Be = 0.0f; }
    float cc = fmaf(Ae, carry, Be);
    #pragma unroll
    for (int i = 0; i < 16; ++i) {
        cc = fmaf(ai[i], cc, bi[i]);
        sh[(seg * 16 + i) * SS + col0] = cc;
    }
    carry = qdpp<0xFF>(cc);   // broadcast quad lane-3 (seg=3) final state
}

__global__ void __launch_bounds__(256)
__attribute__((amdgpu_waves_per_eu(2, 2)))   // 2 waves/EU -> 256 VGPR budget, no spill
gru_fused(const float* __restrict__ x, const int* __restrict__ p,
               const float* __restrict__ w1z0, const float* __restrict__ b1z0,
               const float* __restrict__ w1h0, const float* __restrict__ b1h0,
               const float* __restrict__ w1z1, const float* __restrict__ b1z1,
               const float* __restrict__ w1h1, const float* __restrict__ b1h1,
               const float* __restrict__ w1o,  const float* __restrict__ b1o,
               const float* __restrict__ w2z0, const float* __restrict__ b2z0,
               const float* __restrict__ w2h0, const float* __restrict__ b2h0,
               const float* __restrict__ w2z1, const float* __restrict__ b2z1,
               const float* __restrict__ w2h1, const float* __restrict__ b2h1,
               const float* __restrict__ w2o,  const float* __restrict__ b2o,
               float* __restrict__ out, float* __restrict__ ws)
{
    const int  b  = blockIdx.x;
    const bool pm = (blockIdx.y != 0);

    const float* wz0 = pm ? w2z0 : w1z0;
    const float* bz0 = pm ? b2z0 : b1z0;
    const float* wh0 = pm ? w2h0 : w1h0;
    const float* bh0 = pm ? b2h0 : b1h0;
    const float* wz1 = pm ? w2z1 : w1z1;
    const float* bz1 = pm ? b2z1 : b1z1;
    const float* wh1 = pm ? w2h1 : w1h1;
    const float* bh1 = pm ? b2h1 : b1h1;
    const float* wo  = pm ? w2o  : w1o;
    const float* bov = pm ? b2o  : b1o;

    const int tid  = threadIdx.x;
    const int lane = tid & 63;
    const int tg   = tid >> 6;          // wave id; owns t-block [16*tg, 16*tg+16)
    const int q    = lane >> 4;         // MFMA quad (t sub-block)
    const int n    = lane & 15;         // MFMA col (h low bits)
    const int seg  = lane & 3;          // P1 segment
    const int hidx = (tg << 4) | (lane >> 2);

    __shared__ __align__(16) float s_h[2 * TT * SS];   // double-buffered h0 (swizzled cols)
    __shared__ __align__(16) float s_x[LL];            // staged (pre-permuted) input row
    __shared__ float2 s_w[2][4][HH];                   // per-wave-block scan transforms (A,B)
    __shared__ float s_red[8];

    const float* xrow = x + (size_t)b * LL;

    // ---- stage x row into LDS (pm branch: gather once here, never again) ----
    if (!pm) {
        const float4* x4 = (const float4*)xrow;
        float4* sx4 = (float4*)s_x;
        #pragma unroll
        for (int i = 0; i < LL / 4 / 256; ++i)
            sx4[tid + 256 * i] = x4[tid + 256 * i];
    } else {
        const int4* p4 = (const int4*)p;
        float4* sx4 = (float4*)s_x;
        #pragma unroll
        for (int i = 0; i < LL / 4 / 256; ++i) {
            const int4 v = p4[tid + 256 * i];
            float4 w;
            w.x = xrow[v.x]; w.y = xrow[v.y]; w.z = xrow[v.z]; w.w = xrow[v.w];
            sx4[tid + 256 * i] = w;
        }
    }

    // ---- layer-0 LUT per hidx (x is bernoulli {0,1}) ----
    const float z0v = rcp_(1.0f + __expf(-bz0[hidx]));
    const float z1v = rcp_(1.0f + __expf(-(wz0[hidx] + bz0[hidx])));
    const float a0v = 1.0f - z0v, b0v = z0v * bh0[hidx];
    const float a1v = 1.0f - z1v, b1v = z1v * (wh0[hidx] + bh0[hidx]);

    // ---- layer-1 biases + output weights (MFMA (ht,n) mapping) ----
    float rbz1[4], rbh1[4], rwo4[4];
    #pragma unroll
    for (int ht = 0; ht < 4; ++ht) {
        rbz1[ht] = bz1[ht * 16 + n];
        rbh1[ht] = bh1[ht * 16 + n];
        rwo4[ht] = wo[ht * 16 + n];
    }
    const float bo = bov[0];

    // ---- layer-1 weight B-fragments, RNE hi only ----
    bf16x8 wfz[2][4], wfh[2][4];
    for (int ks = 0; ks < 2; ++ks) {
        for (int ht = 0; ht < 4; ++ht) {
            #pragma unroll
            for (int j = 0; j < 8; ++j) {
                const int kk = ks * 32 + q * 8 + j;
                const int hh = ht * 16 + n;
                wfz[ks][ht][j] = f2bf_rne(wz1[kk * HH + hh]);
                wfh[ks][ht][j] = f2bf_rne(wh1[kk * HH + hh]);
            }
        }
    }

    float carry0 = 0.0f;
    float carry1[4] = {0.0f, 0.0f, 0.0f, 0.0f};   // per ht (h = ht*16+n)
    f32x4 ga[4], gb[4];                            // layer-1 gates (a,b), chunk-persistent
    float Aqe[4], Bqe[4];                          // exclusive-q transforms, chunk-persistent
    float lsum = 0.0f, lsum2 = 0.0f;
    float* outp = out + (pm ? 1 : 0);
    const int t0 = tg * 16;
    const int col0 = hidx ^ ((seg & 1) << 4);      // s_h col swizzle (write side)

    // G2: apply layer-1 scan for chunk cm (gates/Aqe of cm live in registers),
    // fused output projection (DPP shift-reduce over n) + store.
    auto g2_step = [&](int cm) {
        const int buf = cm & 1;
        float Acm[4] = {1,1,1,1}, Bcm[4] = {0,0,0,0};
        float Ap[4], Bp[4];
        #pragma unroll
        for (int w = 0; w < 4; ++w) {
            #pragma unroll
            for (int ht = 0; ht < 4; ++ht) {
                if (w == tg) { Ap[ht] = Acm[ht]; Bp[ht] = Bcm[ht]; }
                const float2 ab = s_w[buf][w][ht * 16 + n];
                Bcm[ht] = fmaf(ab.x, Bcm[ht], ab.y);
                Acm[ht] *= ab.x;
            }
        }
        float vo[4] = {0,0,0,0};
        #pragma unroll
        for (int ht = 0; ht < 4; ++ht) {
            float cc = fmaf(Aqe[ht], fmaf(Ap[ht], carry1[ht], Bp[ht]), Bqe[ht]);
            #pragma unroll
            for (int r = 0; r < 4; ++r) {
                cc = fmaf(ga[ht][r], cc, gb[ht][r]);
                vo[r] = fmaf(cc, rwo4[ht], vo[r]);
            }
            carry1[ht] = fmaf(Acm[ht], carry1[ht], Bcm[ht]);
        }
        // shift-reduce over n (16-lane rows) on the VALU: lane n==15 gets the sum
        #pragma unroll
        for (int r = 0; r < 4; ++r) {
            vo[r] += rshr<1>(vo[r]);
            vo[r] += rshr<2>(vo[r]);
            vo[r] += rshr<4>(vo[r]);
            vo[r] += rshr<8>(vo[r]);
        }
        if (n == 15) {
            #pragma unroll
            for (int r = 0; r < 4; ++r) {
                const float v = vo[r] + bo;
                outp[((size_t)b * LL + cm * TT + t0 + q * 4 + r) * 2] = v;
                lsum += v;
                lsum2 = fmaf(v, v, lsum2);
            }
        }
    };

    __syncthreads();   // s_x staged

    // ---- prologue: P1(0) -> s_h buf 0 ----
    p1_scan(s_x + seg * 16, a0v, b0v, a1v, b1v, seg, col0, carry0, s_h);
    __syncthreads();

    for (int c = 0; c < NCH; ++c) {
        const int cp1 = c + 1;

        // ---- G2(c-1): uses previous chunk's gates (still in registers) ----
        if (c > 0) g2_step(c - 1);

        // ---- G1(c): MFMA + gates + per-wave scan transforms ----
        {
            #pragma unroll
            for (int ht = 0; ht < 4; ++ht) {
                ga[ht] = (f32x4){rbz1[ht], rbz1[ht], rbz1[ht], rbz1[ht]};
                gb[ht] = (f32x4){rbh1[ht], rbh1[ht], rbh1[ht], rbh1[ht]};
            }
            const float* shR = s_h + (c & 1) * (TT * SS);
            const int qs = q ^ ((tg & 1) << 1);   // undo s_h col swizzle (t>>4 == tg)
            #pragma unroll
            for (int ks = 0; ks < 2; ++ks) {
                const float* ap = &shR[(t0 + n) * SS + ks * 32 + qs * 8];
                const float4 av0 = *(const float4*)ap;
                const float4 av1 = *(const float4*)(ap + 4);
                float af[8] = {av0.x, av0.y, av0.z, av0.w, av1.x, av1.y, av1.z, av1.w};
                bf16x8 ahi, alo;
                #pragma unroll
                for (int j = 0; j < 8; ++j) {
                    union { float f; unsigned u; } uf; uf.f = af[j];
                    ahi[j] = (short)(uf.u >> 16);                       // truncate
                    union { unsigned u; float f; } hf; hf.u = uf.u & 0xffff0000u;
                    const float rem = af[j] - hf.f;                     // exact
                    union { float f; unsigned u; } ur; ur.f = rem;
                    alo[j] = (short)(ur.u >> 16);
                }
                #pragma unroll
                for (int ht = 0; ht < 4; ++ht) {
                    ga[ht] = __builtin_amdgcn_mfma_f32_16x16x32_bf16(ahi, wfz[ks][ht], ga[ht], 0, 0, 0);
                    ga[ht] = __builtin_amdgcn_mfma_f32_16x16x32_bf16(alo, wfz[ks][ht], ga[ht], 0, 0, 0);
                    gb[ht] = __builtin_amdgcn_mfma_f32_16x16x32_bf16(ahi, wfh[ks][ht], gb[ht], 0, 0, 0);
                    gb[ht] = __builtin_amdgcn_mfma_f32_16x16x32_bf16(alo, wfh[ks][ht], gb[ht], 0, 0, 0);
                }
            }
            // gates in place: a = 1-sigmoid(v) = rcp(1+exp(v)); b = htl - a*htl
            #pragma unroll
            for (int ht = 0; ht < 4; ++ht) {
                #pragma unroll
                for (int r = 0; r < 4; ++r) {
                    const float v   = ga[ht][r];
                    const float a   = rcp_(1.0f + __expf(v));
                    const float htl = gb[ht][r];
                    ga[ht][r] = a;
                    gb[ht][r] = fmaf(-a, htl, htl);
                }
            }
            // compose own 4 r-steps per ht
            float Aq[4], Bq[4];
            #pragma unroll
            for (int ht = 0; ht < 4; ++ht) {
                float A = 1.0f, B = 0.0f;
                #pragma unroll
                for (int r = 0; r < 4; ++r) {
                    B = fmaf(ga[ht][r], B, gb[ht][r]);
                    A = A * ga[ht][r];
                }
                Aq[ht] = A; Bq[ht] = B;
            }
            // inclusive Hillis-Steele over q (strides 16, 32 lanes)
            #pragma unroll
            for (int ht = 0; ht < 4; ++ht) {
                const float Au = __shfl_up(Aq[ht], 16), Bu = __shfl_up(Bq[ht], 16);
                if (q >= 1) { const float Ac = Aq[ht]; Aq[ht] = Ac * Au; Bq[ht] = fmaf(Ac, Bu, Bq[ht]); }
            }
            #pragma unroll
            for (int ht = 0; ht < 4; ++ht) {
                const float Au = __shfl_up(Aq[ht], 32), Bu = __shfl_up(Bq[ht], 32);
                if (q >= 2) { const float Ac = Aq[ht]; Aq[ht] = Ac * Au; Bq[ht] = fmaf(Ac, Bu, Bq[ht]); }
            }
            // exclusive-q transforms (persist to G2)
            #pragma unroll
            for (int ht = 0; ht < 4; ++ht) {
                const float Ae = __shfl_up(Aq[ht], 16), Be = __shfl_up(Bq[ht], 16);
                Aqe[ht] = (q == 0) ? 1.0f : Ae;
                Bqe[ht] = (q == 0) ? 0.0f : Be;
            }
            // q==3 lanes publish the wave-block inclusive transform
            if (q == 3) {
                #pragma unroll
                for (int ht = 0; ht < 4; ++ht)
                    s_w[c & 1][tg][ht * 16 + n] = make_float2(Aq[ht], Bq[ht]);
            }
        }

        // ---- P1(c+1) -> other s_h buffer (reads staged s_x) ----
        if (cp1 < NCH)
            p1_scan(s_x + cp1 * TT + seg * 16, a0v, b0v, a1v, b1v, seg, col0, carry0,
                    s_h + (cp1 & 1) * (TT * SS));

        __syncthreads();
    }

    // ---- G2 for the last chunk ----
    g2_step(NCH - 1);

    // ---- block partial (sum, sumsq) -> ws slots (plain stores) ----
    #pragma unroll
    for (int o = 32; o; o >>= 1) {
        lsum  += __shfl_down(lsum, o);
        lsum2 += __shfl_down(lsum2, o);
    }
    if (lane == 0) { s_red[tg] = lsum; s_red[4 + tg] = lsum2; }
    __syncthreads();
    if (tid == 0) {
        const int gb2 = b * 2 + (pm ? 1 : 0);
        ws[2 * gb2]     = s_red[0] + s_red[1] + s_red[2] + s_red[3];
        ws[2 * gb2 + 1] = s_red[4] + s_red[5] + s_red[6] + s_red[7];
    }
}

// Fold the 512 block-partials (redundantly per block), normalize in-place.
__global__ void normalize_k(float* __restrict__ out, const float* __restrict__ ws)
{
    __shared__ float s_red[8];
    float s = 0.0f, s2 = 0.0f;
    for (int i = threadIdx.x; i < 2 * BB; i += 256) {
        s  += ws[2 * i];
        s2 += ws[2 * i + 1];
    }
    #pragma unroll
    for (int o = 32; o; o >>= 1) {
        s  += __shfl_down(s, o);
        s2 += __shfl_down(s2, o);
    }
    const int wid = threadIdx.x >> 6;
    if ((threadIdx.x & 63) == 0) { s_red[wid] = s; s_red[4 + wid] = s2; }
    __syncthreads();
    const float tot  = s_red[0] + s_red[1] + s_red[2] + s_red[3];
    const float tot2 = s_red[4] + s_red[5] + s_red[6] + s_red[7];
    const float N    = (float)NTOT;
    const float mean = tot / N;
    const float var  = (tot2 - N * mean * mean) / (N - 1.0f);
    const float inv  = rsqrtf(var);

    const int i = blockIdx.x * blockDim.x + threadIdx.x;   // exactly NTOT/4 threads
    float4* o4 = (float4*)out;
    float4 v = o4[i];
    v.x = (v.x - mean) * inv;
    v.y = (v.y - mean) * inv;
    v.z = (v.z - mean) * inv;
    v.w = (v.w - mean) * inv;
    o4[i] = v;
}

extern "C" void kernel_launch(void* const* d_in, const int* in_sizes, int n_in,
                              void* d_out, int out_size, void* d_ws, size_t ws_size,
                              hipStream_t stream)
{
    (void)in_sizes; (void)n_in; (void)out_size; (void)ws_size;
    const float* x = (const float*)d_in[0];
    const int*   p = (const int*)d_in[1];
    float* out = (float*)d_out;
    float* ws  = (float*)d_ws;

    dim3 grid(BB, 2);
    gru_fused<<<grid, 256, 0, stream>>>(
        x, p,
        (const float*)d_in[2],  (const float*)d_in[3],
        (const float*)d_in[4],  (const float*)d_in[5],
        (const float*)d_in[6],  (const float*)d_in[7],
        (const float*)d_in[8],  (const float*)d_in[9],
        (const float*)d_in[10], (const float*)d_in[11],
        (const float*)d_in[12], (const float*)d_in[13],
        (const float*)d_in[14], (const float*)d_in[15],
        (const float*)d_in[16], (const float*)d_in[17],
        (const float*)d_in[18], (const float*)d_in[19],
        (const float*)d_in[20], (const float*)d_in[21],
        out, ws);

    normalize_k<<<NTOT / 4 / 256, 256, 0, stream>>>(out, ws);
}